// Round 1
// 475.575 us; speedup vs baseline: 1.0174x; 1.0174x over previous
//
#include <hip/hip_runtime.h>
#include <math.h>

// Problem constants (match reference file)
constexpr int U_N = 100000;
constexpr int SI_N = 50000;
constexpr int TI_N = 40000;
constexpr int D = 64;
constexpr int B = 8192;
constexpr int NS = U_N + SI_N;   // 150000 rows in source graph
constexpr int NT = U_N + TI_N;   // 140000 rows in target graph
constexpr int SLOTS = 3 * B;     // compact agg slots: users | pos items | neg items
constexpr int CAP = 48;          // bucket capacity per slot (Poisson lambda ~21; tail -> overflow list)
constexpr int OVCAP = 4096;      // overflow list capacity (statistically never used)
constexpr int NROWS_ALL = U_N + SI_N + TI_N;  // fused dis-loss row space
constexpr int NCHUNK = (NROWS_ALL + 63) / 64; // 64-row chunks for L1 scan
constexpr int DOTS_BLOCKS = B / 4;            // 2048 blocks, 4 waves each -> one wave/sample
constexpr int L1_BLOCKS = 768;

__device__ __forceinline__ float wave_sum(float x) {
#pragma unroll
  for (int m = 32; m; m >>= 1) x += __shfl_xor(x, m, 64);
  return x;
}

__device__ __forceinline__ float softplus_f(float z) {
  return fmaxf(z, 0.f) + log1pf(expf(-fabsf(z)));
}

// ---------------------------------------------------------------------------
// Fused: blocks 0..95 build row->slot maps; block 96 classifies mask layout.
__global__ __launch_bounds__(256) void k_init(
    const int* __restrict__ user, const int* __restrict__ spos, const int* __restrict__ sneg,
    const int* __restrict__ tpos, const int* __restrict__ tneg,
    int* __restrict__ map_s, int* __restrict__ map_t,
    const unsigned char* __restrict__ m, int* __restrict__ det) {
  if (blockIdx.x < 96) {
    int t = blockIdx.x * blockDim.x + threadIdx.x;  // < 3*B exactly
    if (t < B) {
      int u = user[t];
      map_s[u] = t;
      map_t[u] = t;
    } else if (t < 2 * B) {
      int b = t - B;
      map_s[U_N + spos[b]] = t;
      map_t[U_N + tpos[b]] = t;
    } else {
      int b = t - 2 * B;
      map_s[U_N + sneg[b]] = t;
      map_t[U_N + tneg[b]] = t;
    }
    return;
  }
  int t = threadIdx.x;
  int cb = 0, cc = 0;
  for (int i = t; i < B; i += 256) {
    unsigned char v = m[i];
    if ((i & 3) && v) cb++;
    if (v > 1) cc++;
  }
#pragma unroll
  for (int off = 32; off; off >>= 1) {
    cb += __shfl_xor(cb, off, 64);
    cc += __shfl_xor(cc, off, 64);
  }
  __shared__ int sb[4], sc[4];
  if ((t & 63) == 0) { sb[t >> 6] = cb; sc[t >> 6] = cc; }
  __syncthreads();
  if (t == 0) {
    det[0] = sb[0] + sb[1] + sb[2] + sb[3];
    det[1] = sc[0] + sc[1] + sc[2] + sc[3];
  }
}

// ---------------------------------------------------------------------------
// Phase A (both graphs): one THREAD per edge; filter by map; bucket-append the
// FULL PAYLOAD {col, val*drop_int, val*drop_pop} so phase B does no edge-data
// gathers. cols/vals/drops are read here with coalesced index e (streaming).
__global__ __launch_bounds__(256) void k_compact2(
    const int* __restrict__ s_rows, const int* __restrict__ s_cols,
    const float* __restrict__ s_vals,
    const float* __restrict__ dsi, const float* __restrict__ dsp,
    const int* __restrict__ t_rows, const int* __restrict__ t_cols,
    const float* __restrict__ t_vals,
    const float* __restrict__ dti, const float* __restrict__ dtp,
    const int* __restrict__ map_s, const int* __restrict__ map_t,
    int* __restrict__ cnt_s, int* __restrict__ cnt_t,
    int4* __restrict__ bucket_s, int4* __restrict__ bucket_t,
    int* __restrict__ ovcnt_s, int* __restrict__ ovcnt_t,
    int4* __restrict__ ov_s, int4* __restrict__ ov_t, int nnz_s, int nnz_t) {
  int e = blockIdx.x * 256 + threadIdx.x;
  const int* rows;
  const int* cols;
  const float* vals;
  const float* di;
  const float* dp;
  const int* map;
  int* cnt;
  int4* bucket;
  int* ovcnt;
  int4* ov;
  if (e < nnz_s) {
    rows = s_rows; cols = s_cols; vals = s_vals; di = dsi; dp = dsp;
    map = map_s; cnt = cnt_s; bucket = bucket_s; ovcnt = ovcnt_s; ov = ov_s;
  } else {
    e -= nnz_s;
    if (e >= nnz_t) return;
    rows = t_rows; cols = t_cols; vals = t_vals; di = dti; dp = dtp;
    map = map_t; cnt = cnt_t; bucket = bucket_t; ovcnt = ovcnt_t; ov = ov_t;
  }
  int slot = map[rows[e]];
  if (slot < 0) return;
  float v = vals[e];
  float wi = v * di[e];
  float wp = v * dp[e];
  int c = cols[e];
  int pos = atomicAdd(&cnt[slot], 1);
  if (pos < CAP) {
    bucket[(size_t)slot * CAP + pos] =
        make_int4(c, __float_as_int(wi), __float_as_int(wp), 0);
  } else {
    int o = atomicAdd(ovcnt, 1);
    if (o < OVCAP) {
      ov[o] = make_int4(slot, c, __float_as_int(wi), __float_as_int(wp));
    }
  }
}

// ---------------------------------------------------------------------------
// Phase B helper: group g=lane>>4 handles edges k+g..k+12+g; sub=lane&15
// handles dims [4sub,4sub+4). 8 independent float4 loads in flight per iter.
// Dependent-load chain: {cnt, payload} in parallel -> shfl -> embedding gathers.
__device__ __forceinline__ void accum_slot(
    int s, int lane,
    const int* __restrict__ cnt, const int4* __restrict__ bucket,
    const int* __restrict__ ovcnt, const int4* __restrict__ ov,
    const float* __restrict__ eu_i, const float* __restrict__ ei_i,
    const float* __restrict__ eu_p, const float* __restrict__ ei_p,
    float* __restrict__ aggA, float* __restrict__ aggB) {
  // issue both loads unconditionally so they overlap (payload of lanes >= m is
  // masked below; reading allocated-but-unused bucket memory is harmless)
  int li = min(lane, CAP - 1);
  int4 pl = bucket[(size_t)s * CAP + li];
  int m = min(cnt[s], CAP);
  int g = lane >> 4, sub = lane & 15;
  int c = 0;
  float wi = 0.f, wp = 0.f;
  if (lane < m) {
    c = pl.x;
    wi = __int_as_float(pl.y);
    wp = __int_as_float(pl.z);
  }
  float aIx = 0, aIy = 0, aIz = 0, aIw = 0;
  float aPx = 0, aPy = 0, aPz = 0, aPw = 0;
  for (int k = 0; k < m; k += 16) {
    int i0 = k + g, i1 = k + 4 + g, i2 = k + 8 + g, i3 = k + 12 + g;  // <= 47
    int c0 = __shfl(c, i0, 64), c1 = __shfl(c, i1, 64);
    int c2 = __shfl(c, i2, 64), c3 = __shfl(c, i3, 64);
    float wi0 = __shfl(wi, i0, 64), wi1 = __shfl(wi, i1, 64);
    float wi2 = __shfl(wi, i2, 64), wi3 = __shfl(wi, i3, 64);
    float wp0 = __shfl(wp, i0, 64), wp1 = __shfl(wp, i1, 64);
    float wp2 = __shfl(wp, i2, 64), wp3 = __shfl(wp, i3, 64);
    const float* bi0 = (c0 < U_N) ? (eu_i + (size_t)c0 * D) : (ei_i + (size_t)(c0 - U_N) * D);
    const float* bi1 = (c1 < U_N) ? (eu_i + (size_t)c1 * D) : (ei_i + (size_t)(c1 - U_N) * D);
    const float* bi2 = (c2 < U_N) ? (eu_i + (size_t)c2 * D) : (ei_i + (size_t)(c2 - U_N) * D);
    const float* bi3 = (c3 < U_N) ? (eu_i + (size_t)c3 * D) : (ei_i + (size_t)(c3 - U_N) * D);
    const float* bp0 = (c0 < U_N) ? (eu_p + (size_t)c0 * D) : (ei_p + (size_t)(c0 - U_N) * D);
    const float* bp1 = (c1 < U_N) ? (eu_p + (size_t)c1 * D) : (ei_p + (size_t)(c1 - U_N) * D);
    const float* bp2 = (c2 < U_N) ? (eu_p + (size_t)c2 * D) : (ei_p + (size_t)(c2 - U_N) * D);
    const float* bp3 = (c3 < U_N) ? (eu_p + (size_t)c3 * D) : (ei_p + (size_t)(c3 - U_N) * D);
    float4 vI0 = *(const float4*)(bi0 + 4 * sub);
    float4 vI1 = *(const float4*)(bi1 + 4 * sub);
    float4 vI2 = *(const float4*)(bi2 + 4 * sub);
    float4 vI3 = *(const float4*)(bi3 + 4 * sub);
    float4 vP0 = *(const float4*)(bp0 + 4 * sub);
    float4 vP1 = *(const float4*)(bp1 + 4 * sub);
    float4 vP2 = *(const float4*)(bp2 + 4 * sub);
    float4 vP3 = *(const float4*)(bp3 + 4 * sub);
    aIx = fmaf(wi0, vI0.x, aIx); aIy = fmaf(wi0, vI0.y, aIy);
    aIz = fmaf(wi0, vI0.z, aIz); aIw = fmaf(wi0, vI0.w, aIw);
    aIx = fmaf(wi1, vI1.x, aIx); aIy = fmaf(wi1, vI1.y, aIy);
    aIz = fmaf(wi1, vI1.z, aIz); aIw = fmaf(wi1, vI1.w, aIw);
    aIx = fmaf(wi2, vI2.x, aIx); aIy = fmaf(wi2, vI2.y, aIy);
    aIz = fmaf(wi2, vI2.z, aIz); aIw = fmaf(wi2, vI2.w, aIw);
    aIx = fmaf(wi3, vI3.x, aIx); aIy = fmaf(wi3, vI3.y, aIy);
    aIz = fmaf(wi3, vI3.z, aIz); aIw = fmaf(wi3, vI3.w, aIw);
    aPx = fmaf(wp0, vP0.x, aPx); aPy = fmaf(wp0, vP0.y, aPy);
    aPz = fmaf(wp0, vP0.z, aPz); aPw = fmaf(wp0, vP0.w, aPw);
    aPx = fmaf(wp1, vP1.x, aPx); aPy = fmaf(wp1, vP1.y, aPy);
    aPz = fmaf(wp1, vP1.z, aPz); aPw = fmaf(wp1, vP1.w, aPw);
    aPx = fmaf(wp2, vP2.x, aPx); aPy = fmaf(wp2, vP2.y, aPy);
    aPz = fmaf(wp2, vP2.z, aPz); aPw = fmaf(wp2, vP2.w, aPw);
    aPx = fmaf(wp3, vP3.x, aPx); aPy = fmaf(wp3, vP3.y, aPy);
    aPz = fmaf(wp3, vP3.z, aPz); aPw = fmaf(wp3, vP3.w, aPw);
  }
#define XRED(x) x += __shfl_xor(x, 16, 64); x += __shfl_xor(x, 32, 64);
  XRED(aIx) XRED(aIy) XRED(aIz) XRED(aIw)
  XRED(aPx) XRED(aPy) XRED(aPz) XRED(aPw)
#undef XRED
  // overflow fixup by owner wave (normally nov==0); ov entries carry payload
  int nov = min(*ovcnt, OVCAP);
  for (int i = 0; i < nov; ++i) {
    int4 q = ov[i];
    if (q.x == s) {
      int cc = q.y;
      float wwi = __int_as_float(q.z), wwp = __int_as_float(q.w);
      const float* bi = (cc < U_N) ? (eu_i + (size_t)cc * D) : (ei_i + (size_t)(cc - U_N) * D);
      const float* bp = (cc < U_N) ? (eu_p + (size_t)cc * D) : (ei_p + (size_t)(cc - U_N) * D);
      if (lane < 16) {
        float4 vI = *(const float4*)(bi + 4 * sub);
        float4 vP = *(const float4*)(bp + 4 * sub);
        aIx = fmaf(wwi, vI.x, aIx); aIy = fmaf(wwi, vI.y, aIy);
        aIz = fmaf(wwi, vI.z, aIz); aIw = fmaf(wwi, vI.w, aIw);
        aPx = fmaf(wwp, vP.x, aPx); aPy = fmaf(wwp, vP.y, aPy);
        aPz = fmaf(wwp, vP.z, aPz); aPw = fmaf(wwp, vP.w, aPw);
      }
    }
  }
  if (lane < 16) {
    *(float4*)(aggA + (size_t)s * D + 4 * sub) = make_float4(aIx, aIy, aIz, aIw);
    *(float4*)(aggB + (size_t)s * D + 4 * sub) = make_float4(aPx, aPy, aPz, aPw);
  }
}

// Both graphs in one dispatch: sg<SLOTS source, else target.
__global__ __launch_bounds__(256) void k_accum_pair(
    const int* __restrict__ cnt_s, const int4* __restrict__ bucket_s,
    const int* __restrict__ ovcnt_s, const int4* __restrict__ ov_s,
    const int* __restrict__ cnt_t, const int4* __restrict__ bucket_t,
    const int* __restrict__ ovcnt_t, const int4* __restrict__ ov_t,
    const float* __restrict__ su_i, const float* __restrict__ si_i,
    const float* __restrict__ su_p, const float* __restrict__ si_p,
    const float* __restrict__ tu_i, const float* __restrict__ ti_i,
    const float* __restrict__ tu_p, const float* __restrict__ ti_p,
    float* __restrict__ aggSA, float* __restrict__ aggSB,
    float* __restrict__ aggTA, float* __restrict__ aggTB) {
  int lane = threadIdx.x & 63;
  int sg = (blockIdx.x * 256 + threadIdx.x) >> 6;
  if (sg >= 2 * SLOTS) return;
  if (sg < SLOTS) {
    accum_slot(sg, lane, cnt_s, bucket_s, ovcnt_s, ov_s,
               su_i, si_i, su_p, si_p, aggSA, aggSB);
  } else {
    accum_slot(sg - SLOTS, lane, cnt_t, bucket_t, ovcnt_t, ov_t,
               tu_i, ti_i, tu_p, ti_p, aggTA, aggTB);
  }
}

// ---------------------------------------------------------------------------
// Block-completion: device-wide finish. Last block of the tail dispatch reads
// the accumulators and writes the final scalar.
__device__ __forceinline__ void finish_block(float* __restrict__ acc,
                                             int* __restrict__ done_ctr,
                                             float* __restrict__ out,
                                             int nblocks) {
  __threadfence();
  int old = atomicAdd(done_ctr, 1);
  if (old == nblocks - 1) {
    float a0 = atomicAdd(&acc[0], 0.f);
    float n1 = atomicAdd(&acc[1], 0.f);
    float n2 = atomicAdd(&acc[2], 0.f);
    float n3 = atomicAdd(&acc[3], 0.f);
    float n4 = atomicAdd(&acc[4], 0.f);
    float cu = fmaxf(atomicAdd(&acc[5], 0.f), 1.f);
    float cs = fmaxf(atomicAdd(&acc[6], 0.f), 1.f);
    float ct = fmaxf(atomicAdd(&acc[7], 0.f), 1.f);
    float dis = n1 / (cu * (float)D) + n2 / (cs * (float)D) +
                n3 / (cu * (float)D) + n4 / (ct * (float)D);
    out[0] = a0 - 0.01f * dis;
  }
}

// ---------------------------------------------------------------------------
// Fused tail: blocks [0, DOTS_BLOCKS) = one wave per sample, all 8 dots + BPR
// losses; blocks [DOTS_BLOCKS, DOTS_BLOCKS+L1_BLOCKS) = masked-L1 chunk scan.
// Shared completion counter; the last block writes out[0].
__global__ __launch_bounds__(256) void k_tail(
    const int* __restrict__ user,
    const int* __restrict__ spos, const int* __restrict__ sneg,
    const int* __restrict__ tpos, const int* __restrict__ tneg,
    const unsigned char* __restrict__ ms8, const unsigned char* __restrict__ mt8,
    const int* __restrict__ det,
    const float* __restrict__ su_i, const float* __restrict__ si_i,
    const float* __restrict__ su_p, const float* __restrict__ si_p,
    const float* __restrict__ tu_i, const float* __restrict__ ti_i,
    const float* __restrict__ tu_p, const float* __restrict__ ti_p,
    const int* __restrict__ map_s, const int* __restrict__ map_t,
    const float* __restrict__ aggSA, const float* __restrict__ aggSB,
    const float* __restrict__ aggTA, const float* __restrict__ aggTB,
    float* __restrict__ acc, int* __restrict__ done_ctr,
    float* __restrict__ out) {
  int lane = threadIdx.x & 63;
  if (blockIdx.x < DOTS_BLOCKS) {
    // ---- dots + BPR losses ----
    int b = (blockIdx.x * blockDim.x + threadIdx.x) >> 6;
    float contrib = 0.f;
    if (b < B) {
      int u = user[b];
      int ps = spos[b], ns = sneg[b], pt = tpos[b], nt = tneg[b];
      int sus = map_s[u], sps = map_s[U_N + ps], sns = map_s[U_N + ns];
      int sut = map_t[u], spt = map_t[U_N + pt], snt = map_t[U_N + nt];
      // source graph
      float oui = su_i[(size_t)u * D + lane] + aggSA[(size_t)sus * D + lane];
      float oup = su_p[(size_t)u * D + lane] + aggSB[(size_t)sus * D + lane];
      float opi = si_i[(size_t)ps * D + lane] + aggSA[(size_t)sps * D + lane];
      float opp = si_p[(size_t)ps * D + lane] + aggSB[(size_t)sps * D + lane];
      float oni = si_i[(size_t)ns * D + lane] + aggSA[(size_t)sns * D + lane];
      float onp = si_p[(size_t)ns * D + lane] + aggSB[(size_t)sns * D + lane];
      float spi = 0.25f * wave_sum(oui * opi);
      float sni = 0.25f * wave_sum(oui * oni);
      float spp = 0.25f * wave_sum(oup * opp);
      float snp = 0.25f * wave_sum(oup * onp);
      // target graph
      float tui = tu_i[(size_t)u * D + lane] + aggTA[(size_t)sut * D + lane];
      float tup = tu_p[(size_t)u * D + lane] + aggTB[(size_t)sut * D + lane];
      float tpi_ = ti_i[(size_t)pt * D + lane] + aggTA[(size_t)spt * D + lane];
      float tpp_ = ti_p[(size_t)pt * D + lane] + aggTB[(size_t)spt * D + lane];
      float tni_ = ti_i[(size_t)nt * D + lane] + aggTA[(size_t)snt * D + lane];
      float tnp_ = ti_p[(size_t)nt * D + lane] + aggTB[(size_t)snt * D + lane];
      float tpi = 0.25f * wave_sum(tui * tpi_);
      float tni = 0.25f * wave_sum(tui * tni_);
      float tpp = 0.25f * wave_sum(tup * tpp_);
      float tnp = 0.25f * wave_sum(tup * tnp_);
      // masks
      int db = det[0], dc = det[1];
      float ms, mt;
      if (dc > 100) {
        ms = (((const float*)ms8)[b] != 0.f) ? 1.f : 0.f;
        mt = (((const float*)mt8)[b] != 0.f) ? 1.f : 0.f;
      } else if (db > 100) {
        ms = ms8[b] ? 1.f : 0.f;
        mt = mt8[b] ? 1.f : 0.f;
      } else {
        ms = ((const int*)ms8)[b] ? 1.f : 0.f;
        mt = ((const int*)mt8)[b] ? 1.f : 0.f;
      }
      float l_int_s = ms * softplus_f(sni - spi);
      float l_pop_s = ms * softplus_f(spp - snp) + (1.f - ms) * softplus_f(snp - spp);
      float l_tot_s = softplus_f((sni + snp) - (spi + spp));
      float l_int_t = mt * softplus_f(tni - tpi);
      float l_pop_t = mt * softplus_f(tpp - tnp) + (1.f - mt) * softplus_f(tnp - tpp);
      float l_tot_t = softplus_f((tni + tnp) - (tpi + tpp));
      contrib = (l_tot_s + l_tot_t + 0.1f * (l_int_s + l_int_t) +
                 0.1f * (l_pop_s + l_pop_t)) * (1.f / (float)B);
    }
    __shared__ float wsum_[4];
    if (lane == 0) wsum_[threadIdx.x >> 6] = contrib;  // contrib is wave-uniform
    __syncthreads();
    if (threadIdx.x == 0) {
      atomicAdd(&acc[0], wsum_[0] + wsum_[1] + wsum_[2] + wsum_[3]);
      finish_block(acc, done_ctr, out, (int)gridDim.x);
    }
    return;
  }
  // ---- masked-L1 chunk scan ----
  int wave = ((blockIdx.x - DOTS_BLOCKS) * blockDim.x + threadIdx.x) >> 6;
  int nwaves = (L1_BLOCKS * 256) >> 6;
  float a1 = 0.f, a2 = 0.f, a3 = 0.f, a4 = 0.f;
  float c5 = 0.f, c6 = 0.f, c7 = 0.f;
  for (int ch = wave; ch < NCHUNK; ch += nwaves) {
    int r0 = ch * 64;
    int r = r0 + lane;
    int flag = -1;
    if (r < NROWS_ALL) flag = (r < NS) ? map_s[r] : map_t[r - SI_N];
    bool valid = flag >= 0;
    unsigned long long m0 = __ballot(valid && r < U_N);
    unsigned long long m1 = __ballot(valid && r >= U_N && r < NS);
    unsigned long long m2 = __ballot(valid && r >= NS);
    if (lane == 0) {
      c5 += (float)__popcll(m0);
      c6 += (float)__popcll(m1);
      c7 += (float)__popcll(m2);
    }
    unsigned long long mm = m0 | m1 | m2;
    while (mm) {
      int bit = __ffsll((unsigned long long)mm) - 1;
      mm &= mm - 1;
      int rr = r0 + bit;
      if (rr < U_N) {
        size_t o = (size_t)rr * D + lane;
        a1 += fabsf(su_i[o] - su_p[o]);
        a3 += fabsf(tu_i[o] - tu_p[o]);
      } else if (rr < NS) {
        size_t o = (size_t)(rr - U_N) * D + lane;
        a2 += fabsf(si_i[o] - si_p[o]);
      } else {
        size_t o = (size_t)(rr - NS) * D + lane;
        a4 += fabsf(ti_i[o] - ti_p[o]);
      }
    }
  }
  a1 = wave_sum(a1);
  a2 = wave_sum(a2);
  a3 = wave_sum(a3);
  a4 = wave_sum(a4);
  __shared__ float sb[4][8];
  if (lane == 0) {
    int w = threadIdx.x >> 6;
    sb[w][0] = a1; sb[w][1] = a2; sb[w][2] = a3; sb[w][3] = a4;
    sb[w][4] = c5; sb[w][5] = c6; sb[w][6] = c7;
  }
  __syncthreads();
  int t = threadIdx.x;
  if (t < 7) {
    float v = sb[0][t] + sb[1][t] + sb[2][t] + sb[3][t];
    atomicAdd(&acc[1 + t], v);
  }
  __syncthreads();
  if (t == 0) finish_block(acc, done_ctr, out, (int)gridDim.x);
}

// ---------------------------------------------------------------------------
extern "C" void kernel_launch(void* const* d_in, const int* in_sizes, int n_in,
                              void* d_out, int out_size, void* d_ws, size_t ws_size,
                              hipStream_t stream) {
  const int* user = (const int*)d_in[0];
  const int* spos = (const int*)d_in[1];
  const int* sneg = (const int*)d_in[2];
  const int* tpos = (const int*)d_in[3];
  const int* tneg = (const int*)d_in[4];
  const unsigned char* mask_s = (const unsigned char*)d_in[5];
  const unsigned char* mask_t = (const unsigned char*)d_in[6];
  const float* su_int = (const float*)d_in[7];
  const float* si_int = (const float*)d_in[8];
  const float* tu_int = (const float*)d_in[9];
  const float* ti_int = (const float*)d_in[10];
  const float* su_pop = (const float*)d_in[11];
  const float* si_pop = (const float*)d_in[12];
  const float* tu_pop = (const float*)d_in[13];
  const float* ti_pop = (const float*)d_in[14];
  const int* s_rows = (const int*)d_in[15];
  const int* s_cols = (const int*)d_in[16];
  const float* s_vals = (const float*)d_in[17];
  const int* t_rows = (const int*)d_in[18];
  const int* t_cols = (const int*)d_in[19];
  const float* t_vals = (const float*)d_in[20];
  const float* drop_s_int = (const float*)d_in[21];
  const float* drop_t_int = (const float*)d_in[22];
  const float* drop_s_pop = (const float*)d_in[23];
  const float* drop_t_pop = (const float*)d_in[24];
  const int nnz_s = in_sizes[15];
  const int nnz_t = in_sizes[18];

  // Workspace layout (~64 MB). int4 arrays first for 16B alignment.
  int4* bucket_s = (int4*)d_ws;                         // SLOTS*CAP
  int4* bucket_t = bucket_s + (size_t)SLOTS * CAP;      // SLOTS*CAP
  int4* ov_s = bucket_t + (size_t)SLOTS * CAP;          // OVCAP
  int4* ov_t = ov_s + OVCAP;                            // OVCAP
  float* aggSA = (float*)(ov_t + OVCAP);                // SLOTS*D
  float* aggSB = aggSA + (size_t)SLOTS * D;             // SLOTS*D
  float* aggTA = aggSB + (size_t)SLOTS * D;             // SLOTS*D
  float* aggTB = aggTA + (size_t)SLOTS * D;             // SLOTS*D
  float* acc = aggTB + (size_t)SLOTS * D;               // 16 floats
  int* done_ctr = (int*)(acc + 16);                     // 1
  int* det = done_ctr + 1;                              // 2
  int* ovcnt_s = det + 2;                               // 1
  int* ovcnt_t = ovcnt_s + 1;                           // 1
  int* cnt_s = ovcnt_t + 1;                             // SLOTS
  int* cnt_t = cnt_s + SLOTS;                           // SLOTS
  int* map_s = cnt_t + SLOTS;                           // NS
  int* map_t = map_s + NS;                              // NT

  // zero acc..cnt_t (contiguous); maps to -1
  hipMemsetAsync(acc, 0, (size_t)(16 + 1 + 2 + 2 + 2 * SLOTS) * sizeof(int), stream);
  hipMemsetAsync(map_s, 0xFF, (size_t)(NS + NT) * sizeof(int), stream);

  k_init<<<97, 256, 0, stream>>>(user, spos, sneg, tpos, tneg, map_s, map_t, mask_s, det);

  k_compact2<<<(nnz_s + nnz_t + 255) / 256, 256, 0, stream>>>(
      s_rows, s_cols, s_vals, drop_s_int, drop_s_pop,
      t_rows, t_cols, t_vals, drop_t_int, drop_t_pop,
      map_s, map_t, cnt_s, cnt_t, bucket_s, bucket_t,
      ovcnt_s, ovcnt_t, ov_s, ov_t, nnz_s, nnz_t);

  k_accum_pair<<<2 * SLOTS / 4, 256, 0, stream>>>(
      cnt_s, bucket_s, ovcnt_s, ov_s, cnt_t, bucket_t, ovcnt_t, ov_t,
      su_int, si_int, su_pop, si_pop, tu_int, ti_int, tu_pop, ti_pop,
      aggSA, aggSB, aggTA, aggTB);

  k_tail<<<DOTS_BLOCKS + L1_BLOCKS, 256, 0, stream>>>(
      user, spos, sneg, tpos, tneg, mask_s, mask_t, det,
      su_int, si_int, su_pop, si_pop, tu_int, ti_int, tu_pop, ti_pop,
      map_s, map_t, aggSA, aggSB, aggTA, aggTB,
      acc, done_ctr, (float*)d_out);
}

// Round 3
// 463.298 us; speedup vs baseline: 1.0444x; 1.0265x over previous
//
#include <hip/hip_runtime.h>
#include <math.h>

// Problem constants (match reference file)
constexpr int U_N = 100000;
constexpr int SI_N = 50000;
constexpr int TI_N = 40000;
constexpr int D = 64;
constexpr int B = 8192;
constexpr int NS = U_N + SI_N;   // 150000 rows in source graph
constexpr int NT = U_N + TI_N;   // 140000 rows in target graph
constexpr int SLOTS = 3 * B;     // compact agg slots: users | pos items | neg items
constexpr int CAP = 48;          // bucket capacity per slot (Poisson lambda ~21; tail -> overflow list)
constexpr int OVCAP = 4096;      // overflow list capacity (statistically never used)
constexpr int NROWS_ALL = U_N + SI_N + TI_N;  // fused dis-loss row space
constexpr int NCHUNK = (NROWS_ALL + 63) / 64; // 64-row chunks for L1 scan
constexpr int DOTS_BLOCKS = B / 4;            // 2048 blocks, 4 waves each -> one wave/sample
constexpr int L1_BLOCKS = 768;

__device__ __forceinline__ float wave_sum(float x) {
#pragma unroll
  for (int m = 32; m; m >>= 1) x += __shfl_xor(x, m, 64);
  return x;
}

__device__ __forceinline__ float softplus_f(float z) {
  return fmaxf(z, 0.f) + log1pf(expf(-fabsf(z)));
}

// ---------------------------------------------------------------------------
// Fused: blocks 0..95 build row->slot maps; block 96 classifies mask layout.
__global__ __launch_bounds__(256) void k_init(
    const int* __restrict__ user, const int* __restrict__ spos, const int* __restrict__ sneg,
    const int* __restrict__ tpos, const int* __restrict__ tneg,
    int* __restrict__ map_s, int* __restrict__ map_t,
    const unsigned char* __restrict__ m, int* __restrict__ det) {
  if (blockIdx.x < 96) {
    int t = blockIdx.x * blockDim.x + threadIdx.x;  // < 3*B exactly
    if (t < B) {
      int u = user[t];
      map_s[u] = t;
      map_t[u] = t;
    } else if (t < 2 * B) {
      int b = t - B;
      map_s[U_N + spos[b]] = t;
      map_t[U_N + tpos[b]] = t;
    } else {
      int b = t - 2 * B;
      map_s[U_N + sneg[b]] = t;
      map_t[U_N + tneg[b]] = t;
    }
    return;
  }
  int t = threadIdx.x;
  int cb = 0, cc = 0;
  for (int i = t; i < B; i += 256) {
    unsigned char v = m[i];
    if ((i & 3) && v) cb++;
    if (v > 1) cc++;
  }
#pragma unroll
  for (int off = 32; off; off >>= 1) {
    cb += __shfl_xor(cb, off, 64);
    cc += __shfl_xor(cc, off, 64);
  }
  __shared__ int sb[4], sc[4];
  if ((t & 63) == 0) { sb[t >> 6] = cb; sc[t >> 6] = cc; }
  __syncthreads();
  if (t == 0) {
    det[0] = sb[0] + sb[1] + sb[2] + sb[3];
    det[1] = sc[0] + sc[1] + sc[2] + sc[3];
  }
}

// ---------------------------------------------------------------------------
// Phase A (both graphs): FOUR edges per thread. All edge arrays are loaded
// unconditionally as 16B vector loads (streaming rate, independent of the map
// lookup); only the map gathers + atomic + bucket store remain on the
// dependent chain, with 4 independent instances in flight per thread.
// Payload {col, val*drop_int, val*drop_pop} goes into the bucket so phase B
// does no edge-data gathers.
__device__ __forceinline__ void emit_edge(
    int slot, int c, float wi, float wp,
    int* __restrict__ cnt, int4* __restrict__ bucket,
    int* __restrict__ ovcnt, int4* __restrict__ ov) {
  int pos = atomicAdd(&cnt[slot], 1);
  if (pos < CAP) {
    bucket[(size_t)slot * CAP + pos] =
        make_int4(c, __float_as_int(wi), __float_as_int(wp), 0);
  } else {
    int o = atomicAdd(ovcnt, 1);
    if (o < OVCAP) {
      ov[o] = make_int4(slot, c, __float_as_int(wi), __float_as_int(wp));
    }
  }
}

__global__ __launch_bounds__(256) void k_compact4(
    const int* __restrict__ s_rows, const int* __restrict__ s_cols,
    const float* __restrict__ s_vals,
    const float* __restrict__ dsi, const float* __restrict__ dsp,
    const int* __restrict__ t_rows, const int* __restrict__ t_cols,
    const float* __restrict__ t_vals,
    const float* __restrict__ dti, const float* __restrict__ dtp,
    const int* __restrict__ map_s, const int* __restrict__ map_t,
    int* __restrict__ cnt_s, int* __restrict__ cnt_t,
    int4* __restrict__ bucket_s, int4* __restrict__ bucket_t,
    int* __restrict__ ovcnt_s, int* __restrict__ ovcnt_t,
    int4* __restrict__ ov_s, int4* __restrict__ ov_t,
    int nnz_s, int nnz_t, int sblocks) {
  const int* rows;
  const int* cols;
  const float* vals;
  const float* di;
  const float* dp;
  const int* map;
  int* cnt;
  int4* bucket;
  int* ovcnt;
  int4* ov;
  int nnz;
  int blk = blockIdx.x;
  if (blk < sblocks) {
    rows = s_rows; cols = s_cols; vals = s_vals; di = dsi; dp = dsp;
    map = map_s; cnt = cnt_s; bucket = bucket_s; ovcnt = ovcnt_s; ov = ov_s;
    nnz = nnz_s;
  } else {
    blk -= sblocks;
    rows = t_rows; cols = t_cols; vals = t_vals; di = dti; dp = dtp;
    map = map_t; cnt = cnt_t; bucket = bucket_t; ovcnt = ovcnt_t; ov = ov_t;
    nnz = nnz_t;
  }
  int base = (blk * 256 + (int)threadIdx.x) * 4;
  if (base + 4 <= nnz) {
    // independent streaming loads (no dependence on map)
    int4 r4 = *(const int4*)(rows + base);
    int4 c4 = *(const int4*)(cols + base);
    float4 v4 = *(const float4*)(vals + base);
    float4 di4 = *(const float4*)(di + base);
    float4 dp4 = *(const float4*)(dp + base);
    // 4 independent map gathers
    int s0 = map[r4.x];
    int s1 = map[r4.y];
    int s2 = map[r4.z];
    int s3 = map[r4.w];
    if (s0 >= 0) emit_edge(s0, c4.x, v4.x * di4.x, v4.x * dp4.x, cnt, bucket, ovcnt, ov);
    if (s1 >= 0) emit_edge(s1, c4.y, v4.y * di4.y, v4.y * dp4.y, cnt, bucket, ovcnt, ov);
    if (s2 >= 0) emit_edge(s2, c4.z, v4.z * di4.z, v4.z * dp4.z, cnt, bucket, ovcnt, ov);
    if (s3 >= 0) emit_edge(s3, c4.w, v4.w * di4.w, v4.w * dp4.w, cnt, bucket, ovcnt, ov);
  } else {
    for (int e = base; e < nnz; ++e) {
      int slot = map[rows[e]];
      if (slot < 0) continue;
      float v = vals[e];
      emit_edge(slot, cols[e], v * di[e], v * dp[e], cnt, bucket, ovcnt, ov);
    }
  }
}

// ---------------------------------------------------------------------------
// Phase B helper: group g=lane>>4 handles edges k+g..k+12+g; sub=lane&15
// handles dims [4sub,4sub+4). 8 independent float4 loads in flight per iter.
// Dependent-load chain: {cnt, payload} in parallel -> shfl -> embedding gathers.
__device__ __forceinline__ void accum_slot(
    int s, int lane,
    const int* __restrict__ cnt, const int4* __restrict__ bucket,
    const int* __restrict__ ovcnt, const int4* __restrict__ ov,
    const float* __restrict__ eu_i, const float* __restrict__ ei_i,
    const float* __restrict__ eu_p, const float* __restrict__ ei_p,
    float* __restrict__ aggA, float* __restrict__ aggB) {
  // issue both loads unconditionally so they overlap (payload of lanes >= m is
  // masked below; reading allocated-but-unused bucket memory is harmless)
  int li = min(lane, CAP - 1);
  int4 pl = bucket[(size_t)s * CAP + li];
  int m = min(cnt[s], CAP);
  int g = lane >> 4, sub = lane & 15;
  int c = 0;
  float wi = 0.f, wp = 0.f;
  if (lane < m) {
    c = pl.x;
    wi = __int_as_float(pl.y);
    wp = __int_as_float(pl.z);
  }
  float aIx = 0, aIy = 0, aIz = 0, aIw = 0;
  float aPx = 0, aPy = 0, aPz = 0, aPw = 0;
  for (int k = 0; k < m; k += 16) {
    int i0 = k + g, i1 = k + 4 + g, i2 = k + 8 + g, i3 = k + 12 + g;  // <= 47
    int c0 = __shfl(c, i0, 64), c1 = __shfl(c, i1, 64);
    int c2 = __shfl(c, i2, 64), c3 = __shfl(c, i3, 64);
    float wi0 = __shfl(wi, i0, 64), wi1 = __shfl(wi, i1, 64);
    float wi2 = __shfl(wi, i2, 64), wi3 = __shfl(wi, i3, 64);
    float wp0 = __shfl(wp, i0, 64), wp1 = __shfl(wp, i1, 64);
    float wp2 = __shfl(wp, i2, 64), wp3 = __shfl(wp, i3, 64);
    const float* bi0 = (c0 < U_N) ? (eu_i + (size_t)c0 * D) : (ei_i + (size_t)(c0 - U_N) * D);
    const float* bi1 = (c1 < U_N) ? (eu_i + (size_t)c1 * D) : (ei_i + (size_t)(c1 - U_N) * D);
    const float* bi2 = (c2 < U_N) ? (eu_i + (size_t)c2 * D) : (ei_i + (size_t)(c2 - U_N) * D);
    const float* bi3 = (c3 < U_N) ? (eu_i + (size_t)c3 * D) : (ei_i + (size_t)(c3 - U_N) * D);
    const float* bp0 = (c0 < U_N) ? (eu_p + (size_t)c0 * D) : (ei_p + (size_t)(c0 - U_N) * D);
    const float* bp1 = (c1 < U_N) ? (eu_p + (size_t)c1 * D) : (ei_p + (size_t)(c1 - U_N) * D);
    const float* bp2 = (c2 < U_N) ? (eu_p + (size_t)c2 * D) : (ei_p + (size_t)(c2 - U_N) * D);
    const float* bp3 = (c3 < U_N) ? (eu_p + (size_t)c3 * D) : (ei_p + (size_t)(c3 - U_N) * D);
    float4 vI0 = *(const float4*)(bi0 + 4 * sub);
    float4 vI1 = *(const float4*)(bi1 + 4 * sub);
    float4 vI2 = *(const float4*)(bi2 + 4 * sub);
    float4 vI3 = *(const float4*)(bi3 + 4 * sub);
    float4 vP0 = *(const float4*)(bp0 + 4 * sub);
    float4 vP1 = *(const float4*)(bp1 + 4 * sub);
    float4 vP2 = *(const float4*)(bp2 + 4 * sub);
    float4 vP3 = *(const float4*)(bp3 + 4 * sub);
    aIx = fmaf(wi0, vI0.x, aIx); aIy = fmaf(wi0, vI0.y, aIy);
    aIz = fmaf(wi0, vI0.z, aIz); aIw = fmaf(wi0, vI0.w, aIw);
    aIx = fmaf(wi1, vI1.x, aIx); aIy = fmaf(wi1, vI1.y, aIy);
    aIz = fmaf(wi1, vI1.z, aIz); aIw = fmaf(wi1, vI1.w, aIw);
    aIx = fmaf(wi2, vI2.x, aIx); aIy = fmaf(wi2, vI2.y, aIy);
    aIz = fmaf(wi2, vI2.z, aIz); aIw = fmaf(wi2, vI2.w, aIw);
    aIx = fmaf(wi3, vI3.x, aIx); aIy = fmaf(wi3, vI3.y, aIy);
    aIz = fmaf(wi3, vI3.z, aIz); aIw = fmaf(wi3, vI3.w, aIw);
    aPx = fmaf(wp0, vP0.x, aPx); aPy = fmaf(wp0, vP0.y, aPy);
    aPz = fmaf(wp0, vP0.z, aPz); aPw = fmaf(wp0, vP0.w, aPw);
    aPx = fmaf(wp1, vP1.x, aPx); aPy = fmaf(wp1, vP1.y, aPy);
    aPz = fmaf(wp1, vP1.z, aPz); aPw = fmaf(wp1, vP1.w, aPw);
    aPx = fmaf(wp2, vP2.x, aPx); aPy = fmaf(wp2, vP2.y, aPy);
    aPz = fmaf(wp2, vP2.z, aPz); aPw = fmaf(wp2, vP2.w, aPw);
    aPx = fmaf(wp3, vP3.x, aPx); aPy = fmaf(wp3, vP3.y, aPy);
    aPz = fmaf(wp3, vP3.z, aPz); aPw = fmaf(wp3, vP3.w, aPw);
  }
#define XRED(x) x += __shfl_xor(x, 16, 64); x += __shfl_xor(x, 32, 64);
  XRED(aIx) XRED(aIy) XRED(aIz) XRED(aIw)
  XRED(aPx) XRED(aPy) XRED(aPz) XRED(aPw)
#undef XRED
  // overflow fixup by owner wave (normally nov==0); ov entries carry payload
  int nov = min(*ovcnt, OVCAP);
  for (int i = 0; i < nov; ++i) {
    int4 q = ov[i];
    if (q.x == s) {
      int cc = q.y;
      float wwi = __int_as_float(q.z), wwp = __int_as_float(q.w);
      const float* bi = (cc < U_N) ? (eu_i + (size_t)cc * D) : (ei_i + (size_t)(cc - U_N) * D);
      const float* bp = (cc < U_N) ? (eu_p + (size_t)cc * D) : (ei_p + (size_t)(cc - U_N) * D);
      if (lane < 16) {
        float4 vI = *(const float4*)(bi + 4 * sub);
        float4 vP = *(const float4*)(bp + 4 * sub);
        aIx = fmaf(wwi, vI.x, aIx); aIy = fmaf(wwi, vI.y, aIy);
        aIz = fmaf(wwi, vI.z, aIz); aIw = fmaf(wwi, vI.w, aIw);
        aPx = fmaf(wwp, vP.x, aPx); aPy = fmaf(wwp, vP.y, aPy);
        aPz = fmaf(wwp, vP.z, aPz); aPw = fmaf(wwp, vP.w, aPw);
      }
    }
  }
  if (lane < 16) {
    *(float4*)(aggA + (size_t)s * D + 4 * sub) = make_float4(aIx, aIy, aIz, aIw);
    *(float4*)(aggB + (size_t)s * D + 4 * sub) = make_float4(aPx, aPy, aPz, aPw);
  }
}

// Both graphs in one dispatch: sg<SLOTS source, else target.
__global__ __launch_bounds__(256) void k_accum_pair(
    const int* __restrict__ cnt_s, const int4* __restrict__ bucket_s,
    const int* __restrict__ ovcnt_s, const int4* __restrict__ ov_s,
    const int* __restrict__ cnt_t, const int4* __restrict__ bucket_t,
    const int* __restrict__ ovcnt_t, const int4* __restrict__ ov_t,
    const float* __restrict__ su_i, const float* __restrict__ si_i,
    const float* __restrict__ su_p, const float* __restrict__ si_p,
    const float* __restrict__ tu_i, const float* __restrict__ ti_i,
    const float* __restrict__ tu_p, const float* __restrict__ ti_p,
    float* __restrict__ aggSA, float* __restrict__ aggSB,
    float* __restrict__ aggTA, float* __restrict__ aggTB) {
  int lane = threadIdx.x & 63;
  int sg = (blockIdx.x * 256 + threadIdx.x) >> 6;
  if (sg >= 2 * SLOTS) return;
  if (sg < SLOTS) {
    accum_slot(sg, lane, cnt_s, bucket_s, ovcnt_s, ov_s,
               su_i, si_i, su_p, si_p, aggSA, aggSB);
  } else {
    accum_slot(sg - SLOTS, lane, cnt_t, bucket_t, ovcnt_t, ov_t,
               tu_i, ti_i, tu_p, ti_p, aggTA, aggTB);
  }
}

// ---------------------------------------------------------------------------
// Block-completion: device-wide finish. Last block of the tail dispatch reads
// the accumulators and writes the final scalar.
__device__ __forceinline__ void finish_block(float* __restrict__ acc,
                                             int* __restrict__ done_ctr,
                                             float* __restrict__ out,
                                             int nblocks) {
  __threadfence();
  int old = atomicAdd(done_ctr, 1);
  if (old == nblocks - 1) {
    float a0 = atomicAdd(&acc[0], 0.f);
    float n1 = atomicAdd(&acc[1], 0.f);
    float n2 = atomicAdd(&acc[2], 0.f);
    float n3 = atomicAdd(&acc[3], 0.f);
    float n4 = atomicAdd(&acc[4], 0.f);
    float cu = fmaxf(atomicAdd(&acc[5], 0.f), 1.f);
    float cs = fmaxf(atomicAdd(&acc[6], 0.f), 1.f);
    float ct = fmaxf(atomicAdd(&acc[7], 0.f), 1.f);
    float dis = n1 / (cu * (float)D) + n2 / (cs * (float)D) +
                n3 / (cu * (float)D) + n4 / (ct * (float)D);
    out[0] = a0 - 0.01f * dis;
  }
}

// ---------------------------------------------------------------------------
// Fused tail: blocks [0, DOTS_BLOCKS) = one wave per sample, all 8 dots + BPR
// losses; blocks [DOTS_BLOCKS, DOTS_BLOCKS+L1_BLOCKS) = masked-L1 chunk scan.
// Shared completion counter; the last block writes out[0].
__global__ __launch_bounds__(256) void k_tail(
    const int* __restrict__ user,
    const int* __restrict__ spos, const int* __restrict__ sneg,
    const int* __restrict__ tpos, const int* __restrict__ tneg,
    const unsigned char* __restrict__ ms8, const unsigned char* __restrict__ mt8,
    const int* __restrict__ det,
    const float* __restrict__ su_i, const float* __restrict__ si_i,
    const float* __restrict__ su_p, const float* __restrict__ si_p,
    const float* __restrict__ tu_i, const float* __restrict__ ti_i,
    const float* __restrict__ tu_p, const float* __restrict__ ti_p,
    const int* __restrict__ map_s, const int* __restrict__ map_t,
    const float* __restrict__ aggSA, const float* __restrict__ aggSB,
    const float* __restrict__ aggTA, const float* __restrict__ aggTB,
    float* __restrict__ acc, int* __restrict__ done_ctr,
    float* __restrict__ out) {
  int lane = threadIdx.x & 63;
  if (blockIdx.x < DOTS_BLOCKS) {
    // ---- dots + BPR losses ----
    int b = (blockIdx.x * blockDim.x + threadIdx.x) >> 6;
    float contrib = 0.f;
    if (b < B) {
      int u = user[b];
      int ps = spos[b], ns = sneg[b], pt = tpos[b], nt = tneg[b];
      int sus = map_s[u], sps = map_s[U_N + ps], sns = map_s[U_N + ns];
      int sut = map_t[u], spt = map_t[U_N + pt], snt = map_t[U_N + nt];
      // source graph
      float oui = su_i[(size_t)u * D + lane] + aggSA[(size_t)sus * D + lane];
      float oup = su_p[(size_t)u * D + lane] + aggSB[(size_t)sus * D + lane];
      float opi = si_i[(size_t)ps * D + lane] + aggSA[(size_t)sps * D + lane];
      float opp = si_p[(size_t)ps * D + lane] + aggSB[(size_t)sps * D + lane];
      float oni = si_i[(size_t)ns * D + lane] + aggSA[(size_t)sns * D + lane];
      float onp = si_p[(size_t)ns * D + lane] + aggSB[(size_t)sns * D + lane];
      float spi = 0.25f * wave_sum(oui * opi);
      float sni = 0.25f * wave_sum(oui * oni);
      float spp = 0.25f * wave_sum(oup * opp);
      float snp = 0.25f * wave_sum(oup * onp);
      // target graph
      float tui = tu_i[(size_t)u * D + lane] + aggTA[(size_t)sut * D + lane];
      float tup = tu_p[(size_t)u * D + lane] + aggTB[(size_t)sut * D + lane];
      float tpi_ = ti_i[(size_t)pt * D + lane] + aggTA[(size_t)spt * D + lane];
      float tpp_ = ti_p[(size_t)pt * D + lane] + aggTB[(size_t)spt * D + lane];
      float tni_ = ti_i[(size_t)nt * D + lane] + aggTA[(size_t)snt * D + lane];
      float tnp_ = ti_p[(size_t)nt * D + lane] + aggTB[(size_t)snt * D + lane];
      float tpi = 0.25f * wave_sum(tui * tpi_);
      float tni = 0.25f * wave_sum(tui * tni_);
      float tpp = 0.25f * wave_sum(tup * tpp_);
      float tnp = 0.25f * wave_sum(tup * tnp_);
      // masks
      int db = det[0], dc = det[1];
      float ms, mt;
      if (dc > 100) {
        ms = (((const float*)ms8)[b] != 0.f) ? 1.f : 0.f;
        mt = (((const float*)mt8)[b] != 0.f) ? 1.f : 0.f;
      } else if (db > 100) {
        ms = ms8[b] ? 1.f : 0.f;
        mt = mt8[b] ? 1.f : 0.f;
      } else {
        ms = ((const int*)ms8)[b] ? 1.f : 0.f;
        mt = ((const int*)mt8)[b] ? 1.f : 0.f;
      }
      float l_int_s = ms * softplus_f(sni - spi);
      float l_pop_s = ms * softplus_f(spp - snp) + (1.f - ms) * softplus_f(snp - spp);
      float l_tot_s = softplus_f((sni + snp) - (spi + spp));
      float l_int_t = mt * softplus_f(tni - tpi);
      float l_pop_t = mt * softplus_f(tpp - tnp) + (1.f - mt) * softplus_f(tnp - tpp);
      float l_tot_t = softplus_f((tni + tnp) - (tpi + tpp));
      contrib = (l_tot_s + l_tot_t + 0.1f * (l_int_s + l_int_t) +
                 0.1f * (l_pop_s + l_pop_t)) * (1.f / (float)B);
    }
    __shared__ float wsum_[4];
    if (lane == 0) wsum_[threadIdx.x >> 6] = contrib;  // contrib is wave-uniform
    __syncthreads();
    if (threadIdx.x == 0) {
      atomicAdd(&acc[0], wsum_[0] + wsum_[1] + wsum_[2] + wsum_[3]);
      finish_block(acc, done_ctr, out, (int)gridDim.x);
    }
    return;
  }
  // ---- masked-L1 chunk scan ----
  int wave = ((blockIdx.x - DOTS_BLOCKS) * blockDim.x + threadIdx.x) >> 6;
  int nwaves = (L1_BLOCKS * 256) >> 6;
  float a1 = 0.f, a2 = 0.f, a3 = 0.f, a4 = 0.f;
  float c5 = 0.f, c6 = 0.f, c7 = 0.f;
  for (int ch = wave; ch < NCHUNK; ch += nwaves) {
    int r0 = ch * 64;
    int r = r0 + lane;
    int flag = -1;
    if (r < NROWS_ALL) flag = (r < NS) ? map_s[r] : map_t[r - SI_N];
    bool valid = flag >= 0;
    unsigned long long m0 = __ballot(valid && r < U_N);
    unsigned long long m1 = __ballot(valid && r >= U_N && r < NS);
    unsigned long long m2 = __ballot(valid && r >= NS);
    if (lane == 0) {
      c5 += (float)__popcll(m0);
      c6 += (float)__popcll(m1);
      c7 += (float)__popcll(m2);
    }
    unsigned long long mm = m0 | m1 | m2;
    while (mm) {
      int bit = __ffsll((unsigned long long)mm) - 1;
      mm &= mm - 1;
      int rr = r0 + bit;
      if (rr < U_N) {
        size_t o = (size_t)rr * D + lane;
        a1 += fabsf(su_i[o] - su_p[o]);
        a3 += fabsf(tu_i[o] - tu_p[o]);
      } else if (rr < NS) {
        size_t o = (size_t)(rr - U_N) * D + lane;
        a2 += fabsf(si_i[o] - si_p[o]);
      } else {
        size_t o = (size_t)(rr - NS) * D + lane;
        a4 += fabsf(ti_i[o] - ti_p[o]);
      }
    }
  }
  a1 = wave_sum(a1);
  a2 = wave_sum(a2);
  a3 = wave_sum(a3);
  a4 = wave_sum(a4);
  __shared__ float sb[4][8];
  if (lane == 0) {
    int w = threadIdx.x >> 6;
    sb[w][0] = a1; sb[w][1] = a2; sb[w][2] = a3; sb[w][3] = a4;
    sb[w][4] = c5; sb[w][5] = c6; sb[w][6] = c7;
  }
  __syncthreads();
  int t = threadIdx.x;
  if (t < 7) {
    float v = sb[0][t] + sb[1][t] + sb[2][t] + sb[3][t];
    atomicAdd(&acc[1 + t], v);
  }
  __syncthreads();
  if (t == 0) finish_block(acc, done_ctr, out, (int)gridDim.x);
}

// ---------------------------------------------------------------------------
extern "C" void kernel_launch(void* const* d_in, const int* in_sizes, int n_in,
                              void* d_out, int out_size, void* d_ws, size_t ws_size,
                              hipStream_t stream) {
  const int* user = (const int*)d_in[0];
  const int* spos = (const int*)d_in[1];
  const int* sneg = (const int*)d_in[2];
  const int* tpos = (const int*)d_in[3];
  const int* tneg = (const int*)d_in[4];
  const unsigned char* mask_s = (const unsigned char*)d_in[5];
  const unsigned char* mask_t = (const unsigned char*)d_in[6];
  const float* su_int = (const float*)d_in[7];
  const float* si_int = (const float*)d_in[8];
  const float* tu_int = (const float*)d_in[9];
  const float* ti_int = (const float*)d_in[10];
  const float* su_pop = (const float*)d_in[11];
  const float* si_pop = (const float*)d_in[12];
  const float* tu_pop = (const float*)d_in[13];
  const float* ti_pop = (const float*)d_in[14];
  const int* s_rows = (const int*)d_in[15];
  const int* s_cols = (const int*)d_in[16];
  const float* s_vals = (const float*)d_in[17];
  const int* t_rows = (const int*)d_in[18];
  const int* t_cols = (const int*)d_in[19];
  const float* t_vals = (const float*)d_in[20];
  const float* drop_s_int = (const float*)d_in[21];
  const float* drop_t_int = (const float*)d_in[22];
  const float* drop_s_pop = (const float*)d_in[23];
  const float* drop_t_pop = (const float*)d_in[24];
  const int nnz_s = in_sizes[15];
  const int nnz_t = in_sizes[18];

  // Workspace layout (~64 MB). int4 arrays first for 16B alignment.
  int4* bucket_s = (int4*)d_ws;                         // SLOTS*CAP
  int4* bucket_t = bucket_s + (size_t)SLOTS * CAP;      // SLOTS*CAP
  int4* ov_s = bucket_t + (size_t)SLOTS * CAP;          // OVCAP
  int4* ov_t = ov_s + OVCAP;                            // OVCAP
  float* aggSA = (float*)(ov_t + OVCAP);                // SLOTS*D
  float* aggSB = aggSA + (size_t)SLOTS * D;             // SLOTS*D
  float* aggTA = aggSB + (size_t)SLOTS * D;             // SLOTS*D
  float* aggTB = aggTA + (size_t)SLOTS * D;             // SLOTS*D
  float* acc = aggTB + (size_t)SLOTS * D;               // 16 floats
  int* done_ctr = (int*)(acc + 16);                     // 1
  int* det = done_ctr + 1;                              // 2
  int* ovcnt_s = det + 2;                               // 1
  int* ovcnt_t = ovcnt_s + 1;                           // 1
  int* cnt_s = ovcnt_t + 1;                             // SLOTS
  int* cnt_t = cnt_s + SLOTS;                           // SLOTS
  int* map_s = cnt_t + SLOTS;                           // NS
  int* map_t = map_s + NS;                              // NT

  // zero acc..cnt_t (contiguous); maps to -1
  hipMemsetAsync(acc, 0, (size_t)(16 + 1 + 2 + 2 + 2 * SLOTS) * sizeof(int), stream);
  hipMemsetAsync(map_s, 0xFF, (size_t)(NS + NT) * sizeof(int), stream);

  k_init<<<97, 256, 0, stream>>>(user, spos, sneg, tpos, tneg, map_s, map_t, mask_s, det);

  int sblocks = (nnz_s + 1023) / 1024;
  int tblocks = (nnz_t + 1023) / 1024;
  k_compact4<<<sblocks + tblocks, 256, 0, stream>>>(
      s_rows, s_cols, s_vals, drop_s_int, drop_s_pop,
      t_rows, t_cols, t_vals, drop_t_int, drop_t_pop,
      map_s, map_t, cnt_s, cnt_t, bucket_s, bucket_t,
      ovcnt_s, ovcnt_t, ov_s, ov_t, nnz_s, nnz_t, sblocks);

  k_accum_pair<<<2 * SLOTS / 4, 256, 0, stream>>>(
      cnt_s, bucket_s, ovcnt_s, ov_s, cnt_t, bucket_t, ovcnt_t, ov_t,
      su_int, si_int, su_pop, si_pop, tu_int, ti_int, tu_pop, ti_pop,
      aggSA, aggSB, aggTA, aggTB);

  k_tail<<<DOTS_BLOCKS + L1_BLOCKS, 256, 0, stream>>>(
      user, spos, sneg, tpos, tneg, mask_s, mask_t, det,
      su_int, si_int, su_pop, si_pop, tu_int, ti_int, tu_pop, ti_pop,
      map_s, map_t, aggSA, aggSB, aggTA, aggTB,
      acc, done_ctr, (float*)d_out);
}

// Round 4
// 404.686 us; speedup vs baseline: 1.1956x; 1.1448x over previous
//
#include <hip/hip_runtime.h>
#include <math.h>

// Problem constants (match reference file)
constexpr int U_N = 100000;
constexpr int SI_N = 50000;
constexpr int TI_N = 40000;
constexpr int D = 64;
constexpr int B = 8192;
constexpr int NS = U_N + SI_N;   // 150000 rows in source graph
constexpr int NT = U_N + TI_N;   // 140000 rows in target graph
constexpr int SLOTS = 3 * B;     // compact agg slots: users | pos items | neg items
constexpr int CAP = 48;          // bucket capacity per slot (Poisson lambda ~21; tail -> overflow list)
constexpr int OVCAP = 4096;      // overflow list capacity (statistically never used)
constexpr int NROWS_ALL = U_N + SI_N + TI_N;  // fused dis-loss row space
constexpr int NCHUNK = (NROWS_ALL + 63) / 64; // 64-row chunks for L1 scan
constexpr int DOTS_BLOCKS = B / 4;            // 2048 blocks, 4 waves each -> one wave/sample
constexpr int L1_BLOCKS = 768;

__device__ __forceinline__ float wave_sum(float x) {
#pragma unroll
  for (int m = 32; m; m >>= 1) x += __shfl_xor(x, m, 64);
  return x;
}

__device__ __forceinline__ float softplus_f(float z) {
  return fmaxf(z, 0.f) + log1pf(expf(-fabsf(z)));
}

// ---------------------------------------------------------------------------
// Fused: blocks 0..95 build row->slot maps; block 96 classifies mask layout.
__global__ __launch_bounds__(256) void k_init(
    const int* __restrict__ user, const int* __restrict__ spos, const int* __restrict__ sneg,
    const int* __restrict__ tpos, const int* __restrict__ tneg,
    int* __restrict__ map_s, int* __restrict__ map_t,
    const unsigned char* __restrict__ m, int* __restrict__ det) {
  if (blockIdx.x < 96) {
    int t = blockIdx.x * blockDim.x + threadIdx.x;  // < 3*B exactly
    if (t < B) {
      int u = user[t];
      map_s[u] = t;
      map_t[u] = t;
    } else if (t < 2 * B) {
      int b = t - B;
      map_s[U_N + spos[b]] = t;
      map_t[U_N + tpos[b]] = t;
    } else {
      int b = t - 2 * B;
      map_s[U_N + sneg[b]] = t;
      map_t[U_N + tneg[b]] = t;
    }
    return;
  }
  int t = threadIdx.x;
  int cb = 0, cc = 0;
  for (int i = t; i < B; i += 256) {
    unsigned char v = m[i];
    if ((i & 3) && v) cb++;
    if (v > 1) cc++;
  }
#pragma unroll
  for (int off = 32; off; off >>= 1) {
    cb += __shfl_xor(cb, off, 64);
    cc += __shfl_xor(cc, off, 64);
  }
  __shared__ int sb[4], sc[4];
  if ((t & 63) == 0) { sb[t >> 6] = cb; sc[t >> 6] = cc; }
  __syncthreads();
  if (t == 0) {
    det[0] = sb[0] + sb[1] + sb[2] + sb[3];
    det[1] = sc[0] + sc[1] + sc[2] + sc[3];
  }
}

// ---------------------------------------------------------------------------
// Phase A (both graphs): FOUR edges per thread. All edge arrays are loaded
// unconditionally as 16B vector loads (streaming rate, independent of the map
// lookup); only the map gathers + atomic + bucket store remain on the
// dependent chain, with 4 independent instances in flight per thread.
// Payload {col, val*drop_int, val*drop_pop} goes into the bucket so phase B
// does no edge-data gathers.
__device__ __forceinline__ void emit_edge(
    int slot, int c, float wi, float wp,
    int* __restrict__ cnt, int4* __restrict__ bucket,
    int* __restrict__ ovcnt, int4* __restrict__ ov) {
  int pos = atomicAdd(&cnt[slot], 1);
  if (pos < CAP) {
    bucket[(size_t)slot * CAP + pos] =
        make_int4(c, __float_as_int(wi), __float_as_int(wp), 0);
  } else {
    int o = atomicAdd(ovcnt, 1);
    if (o < OVCAP) {
      ov[o] = make_int4(slot, c, __float_as_int(wi), __float_as_int(wp));
    }
  }
}

__global__ __launch_bounds__(256) void k_compact4(
    const int* __restrict__ s_rows, const int* __restrict__ s_cols,
    const float* __restrict__ s_vals,
    const float* __restrict__ dsi, const float* __restrict__ dsp,
    const int* __restrict__ t_rows, const int* __restrict__ t_cols,
    const float* __restrict__ t_vals,
    const float* __restrict__ dti, const float* __restrict__ dtp,
    const int* __restrict__ map_s, const int* __restrict__ map_t,
    int* __restrict__ cnt_s, int* __restrict__ cnt_t,
    int4* __restrict__ bucket_s, int4* __restrict__ bucket_t,
    int* __restrict__ ovcnt_s, int* __restrict__ ovcnt_t,
    int4* __restrict__ ov_s, int4* __restrict__ ov_t,
    int nnz_s, int nnz_t, int sblocks) {
  const int* rows;
  const int* cols;
  const float* vals;
  const float* di;
  const float* dp;
  const int* map;
  int* cnt;
  int4* bucket;
  int* ovcnt;
  int4* ov;
  int nnz;
  int blk = blockIdx.x;
  if (blk < sblocks) {
    rows = s_rows; cols = s_cols; vals = s_vals; di = dsi; dp = dsp;
    map = map_s; cnt = cnt_s; bucket = bucket_s; ovcnt = ovcnt_s; ov = ov_s;
    nnz = nnz_s;
  } else {
    blk -= sblocks;
    rows = t_rows; cols = t_cols; vals = t_vals; di = dti; dp = dtp;
    map = map_t; cnt = cnt_t; bucket = bucket_t; ovcnt = ovcnt_t; ov = ov_t;
    nnz = nnz_t;
  }
  int base = (blk * 256 + (int)threadIdx.x) * 4;
  if (base + 4 <= nnz) {
    // independent streaming loads (no dependence on map)
    int4 r4 = *(const int4*)(rows + base);
    int4 c4 = *(const int4*)(cols + base);
    float4 v4 = *(const float4*)(vals + base);
    float4 di4 = *(const float4*)(di + base);
    float4 dp4 = *(const float4*)(dp + base);
    // 4 independent map gathers
    int s0 = map[r4.x];
    int s1 = map[r4.y];
    int s2 = map[r4.z];
    int s3 = map[r4.w];
    if (s0 >= 0) emit_edge(s0, c4.x, v4.x * di4.x, v4.x * dp4.x, cnt, bucket, ovcnt, ov);
    if (s1 >= 0) emit_edge(s1, c4.y, v4.y * di4.y, v4.y * dp4.y, cnt, bucket, ovcnt, ov);
    if (s2 >= 0) emit_edge(s2, c4.z, v4.z * di4.z, v4.z * dp4.z, cnt, bucket, ovcnt, ov);
    if (s3 >= 0) emit_edge(s3, c4.w, v4.w * di4.w, v4.w * dp4.w, cnt, bucket, ovcnt, ov);
  } else {
    for (int e = base; e < nnz; ++e) {
      int slot = map[rows[e]];
      if (slot < 0) continue;
      float v = vals[e];
      emit_edge(slot, cols[e], v * di[e], v * dp[e], cnt, bucket, ovcnt, ov);
    }
  }
}

// ---------------------------------------------------------------------------
// Phase B helper: group g=lane>>4 handles edges k+g..k+12+g; sub=lane&15
// handles dims [4sub,4sub+4). 8 independent float4 loads in flight per iter.
// Dependent-load chain: {cnt, payload} in parallel -> shfl -> embedding gathers.
__device__ __forceinline__ void accum_slot(
    int s, int lane,
    const int* __restrict__ cnt, const int4* __restrict__ bucket,
    const int* __restrict__ ovcnt, const int4* __restrict__ ov,
    const float* __restrict__ eu_i, const float* __restrict__ ei_i,
    const float* __restrict__ eu_p, const float* __restrict__ ei_p,
    float* __restrict__ aggA, float* __restrict__ aggB) {
  // issue both loads unconditionally so they overlap (payload of lanes >= m is
  // masked below; reading allocated-but-unused bucket memory is harmless)
  int li = min(lane, CAP - 1);
  int4 pl = bucket[(size_t)s * CAP + li];
  int m = min(cnt[s], CAP);
  int g = lane >> 4, sub = lane & 15;
  int c = 0;
  float wi = 0.f, wp = 0.f;
  if (lane < m) {
    c = pl.x;
    wi = __int_as_float(pl.y);
    wp = __int_as_float(pl.z);
  }
  float aIx = 0, aIy = 0, aIz = 0, aIw = 0;
  float aPx = 0, aPy = 0, aPz = 0, aPw = 0;
  for (int k = 0; k < m; k += 16) {
    int i0 = k + g, i1 = k + 4 + g, i2 = k + 8 + g, i3 = k + 12 + g;  // <= 47
    int c0 = __shfl(c, i0, 64), c1 = __shfl(c, i1, 64);
    int c2 = __shfl(c, i2, 64), c3 = __shfl(c, i3, 64);
    float wi0 = __shfl(wi, i0, 64), wi1 = __shfl(wi, i1, 64);
    float wi2 = __shfl(wi, i2, 64), wi3 = __shfl(wi, i3, 64);
    float wp0 = __shfl(wp, i0, 64), wp1 = __shfl(wp, i1, 64);
    float wp2 = __shfl(wp, i2, 64), wp3 = __shfl(wp, i3, 64);
    const float* bi0 = (c0 < U_N) ? (eu_i + (size_t)c0 * D) : (ei_i + (size_t)(c0 - U_N) * D);
    const float* bi1 = (c1 < U_N) ? (eu_i + (size_t)c1 * D) : (ei_i + (size_t)(c1 - U_N) * D);
    const float* bi2 = (c2 < U_N) ? (eu_i + (size_t)c2 * D) : (ei_i + (size_t)(c2 - U_N) * D);
    const float* bi3 = (c3 < U_N) ? (eu_i + (size_t)c3 * D) : (ei_i + (size_t)(c3 - U_N) * D);
    const float* bp0 = (c0 < U_N) ? (eu_p + (size_t)c0 * D) : (ei_p + (size_t)(c0 - U_N) * D);
    const float* bp1 = (c1 < U_N) ? (eu_p + (size_t)c1 * D) : (ei_p + (size_t)(c1 - U_N) * D);
    const float* bp2 = (c2 < U_N) ? (eu_p + (size_t)c2 * D) : (ei_p + (size_t)(c2 - U_N) * D);
    const float* bp3 = (c3 < U_N) ? (eu_p + (size_t)c3 * D) : (ei_p + (size_t)(c3 - U_N) * D);
    float4 vI0 = *(const float4*)(bi0 + 4 * sub);
    float4 vI1 = *(const float4*)(bi1 + 4 * sub);
    float4 vI2 = *(const float4*)(bi2 + 4 * sub);
    float4 vI3 = *(const float4*)(bi3 + 4 * sub);
    float4 vP0 = *(const float4*)(bp0 + 4 * sub);
    float4 vP1 = *(const float4*)(bp1 + 4 * sub);
    float4 vP2 = *(const float4*)(bp2 + 4 * sub);
    float4 vP3 = *(const float4*)(bp3 + 4 * sub);
    aIx = fmaf(wi0, vI0.x, aIx); aIy = fmaf(wi0, vI0.y, aIy);
    aIz = fmaf(wi0, vI0.z, aIz); aIw = fmaf(wi0, vI0.w, aIw);
    aIx = fmaf(wi1, vI1.x, aIx); aIy = fmaf(wi1, vI1.y, aIy);
    aIz = fmaf(wi1, vI1.z, aIz); aIw = fmaf(wi1, vI1.w, aIw);
    aIx = fmaf(wi2, vI2.x, aIx); aIy = fmaf(wi2, vI2.y, aIy);
    aIz = fmaf(wi2, vI2.z, aIz); aIw = fmaf(wi2, vI2.w, aIw);
    aIx = fmaf(wi3, vI3.x, aIx); aIy = fmaf(wi3, vI3.y, aIy);
    aIz = fmaf(wi3, vI3.z, aIz); aIw = fmaf(wi3, vI3.w, aIw);
    aPx = fmaf(wp0, vP0.x, aPx); aPy = fmaf(wp0, vP0.y, aPy);
    aPz = fmaf(wp0, vP0.z, aPz); aPw = fmaf(wp0, vP0.w, aPw);
    aPx = fmaf(wp1, vP1.x, aPx); aPy = fmaf(wp1, vP1.y, aPy);
    aPz = fmaf(wp1, vP1.z, aPz); aPw = fmaf(wp1, vP1.w, aPw);
    aPx = fmaf(wp2, vP2.x, aPx); aPy = fmaf(wp2, vP2.y, aPy);
    aPz = fmaf(wp2, vP2.z, aPz); aPw = fmaf(wp2, vP2.w, aPw);
    aPx = fmaf(wp3, vP3.x, aPx); aPy = fmaf(wp3, vP3.y, aPy);
    aPz = fmaf(wp3, vP3.z, aPz); aPw = fmaf(wp3, vP3.w, aPw);
  }
#define XRED(x) x += __shfl_xor(x, 16, 64); x += __shfl_xor(x, 32, 64);
  XRED(aIx) XRED(aIy) XRED(aIz) XRED(aIw)
  XRED(aPx) XRED(aPy) XRED(aPz) XRED(aPw)
#undef XRED
  // overflow fixup by owner wave (normally nov==0); ov entries carry payload
  int nov = min(*ovcnt, OVCAP);
  for (int i = 0; i < nov; ++i) {
    int4 q = ov[i];
    if (q.x == s) {
      int cc = q.y;
      float wwi = __int_as_float(q.z), wwp = __int_as_float(q.w);
      const float* bi = (cc < U_N) ? (eu_i + (size_t)cc * D) : (ei_i + (size_t)(cc - U_N) * D);
      const float* bp = (cc < U_N) ? (eu_p + (size_t)cc * D) : (ei_p + (size_t)(cc - U_N) * D);
      if (lane < 16) {
        float4 vI = *(const float4*)(bi + 4 * sub);
        float4 vP = *(const float4*)(bp + 4 * sub);
        aIx = fmaf(wwi, vI.x, aIx); aIy = fmaf(wwi, vI.y, aIy);
        aIz = fmaf(wwi, vI.z, aIz); aIw = fmaf(wwi, vI.w, aIw);
        aPx = fmaf(wwp, vP.x, aPx); aPy = fmaf(wwp, vP.y, aPy);
        aPz = fmaf(wwp, vP.z, aPz); aPw = fmaf(wwp, vP.w, aPw);
      }
    }
  }
  if (lane < 16) {
    *(float4*)(aggA + (size_t)s * D + 4 * sub) = make_float4(aIx, aIy, aIz, aIw);
    *(float4*)(aggB + (size_t)s * D + 4 * sub) = make_float4(aPx, aPy, aPz, aPw);
  }
}

// Both graphs in one dispatch: sg<SLOTS source, else target.
__global__ __launch_bounds__(256) void k_accum_pair(
    const int* __restrict__ cnt_s, const int4* __restrict__ bucket_s,
    const int* __restrict__ ovcnt_s, const int4* __restrict__ ov_s,
    const int* __restrict__ cnt_t, const int4* __restrict__ bucket_t,
    const int* __restrict__ ovcnt_t, const int4* __restrict__ ov_t,
    const float* __restrict__ su_i, const float* __restrict__ si_i,
    const float* __restrict__ su_p, const float* __restrict__ si_p,
    const float* __restrict__ tu_i, const float* __restrict__ ti_i,
    const float* __restrict__ tu_p, const float* __restrict__ ti_p,
    float* __restrict__ aggSA, float* __restrict__ aggSB,
    float* __restrict__ aggTA, float* __restrict__ aggTB) {
  int lane = threadIdx.x & 63;
  int sg = (blockIdx.x * 256 + threadIdx.x) >> 6;
  if (sg >= 2 * SLOTS) return;
  if (sg < SLOTS) {
    accum_slot(sg, lane, cnt_s, bucket_s, ovcnt_s, ov_s,
               su_i, si_i, su_p, si_p, aggSA, aggSB);
  } else {
    accum_slot(sg - SLOTS, lane, cnt_t, bucket_t, ovcnt_t, ov_t,
               tu_i, ti_i, tu_p, ti_p, aggTA, aggTB);
  }
}

// ---------------------------------------------------------------------------
// Fused tail: blocks [0, DOTS_BLOCKS) = one wave per sample, all 8 dots + BPR
// losses; blocks [DOTS_BLOCKS, DOTS_BLOCKS+L1_BLOCKS) = masked-L1 chunk scan.
// NO contended atomics: every block writes plain stores to its OWN partial
// slots; a separate 1-block k_finish kernel (stream-ordered) reduces them.
__global__ __launch_bounds__(256) void k_tail(
    const int* __restrict__ user,
    const int* __restrict__ spos, const int* __restrict__ sneg,
    const int* __restrict__ tpos, const int* __restrict__ tneg,
    const unsigned char* __restrict__ ms8, const unsigned char* __restrict__ mt8,
    const int* __restrict__ det,
    const float* __restrict__ su_i, const float* __restrict__ si_i,
    const float* __restrict__ su_p, const float* __restrict__ si_p,
    const float* __restrict__ tu_i, const float* __restrict__ ti_i,
    const float* __restrict__ tu_p, const float* __restrict__ ti_p,
    const int* __restrict__ map_s, const int* __restrict__ map_t,
    const float* __restrict__ aggSA, const float* __restrict__ aggSB,
    const float* __restrict__ aggTA, const float* __restrict__ aggTB,
    float* __restrict__ dots_part, float* __restrict__ l1_part) {
  int lane = threadIdx.x & 63;
  if (blockIdx.x < DOTS_BLOCKS) {
    // ---- dots + BPR losses ----
    int b = (blockIdx.x * blockDim.x + threadIdx.x) >> 6;
    float contrib = 0.f;
    {
      int u = user[b];
      int ps = spos[b], ns = sneg[b], pt = tpos[b], nt = tneg[b];
      int sus = map_s[u], sps = map_s[U_N + ps], sns = map_s[U_N + ns];
      int sut = map_t[u], spt = map_t[U_N + pt], snt = map_t[U_N + nt];
      // source graph
      float oui = su_i[(size_t)u * D + lane] + aggSA[(size_t)sus * D + lane];
      float oup = su_p[(size_t)u * D + lane] + aggSB[(size_t)sus * D + lane];
      float opi = si_i[(size_t)ps * D + lane] + aggSA[(size_t)sps * D + lane];
      float opp = si_p[(size_t)ps * D + lane] + aggSB[(size_t)sps * D + lane];
      float oni = si_i[(size_t)ns * D + lane] + aggSA[(size_t)sns * D + lane];
      float onp = si_p[(size_t)ns * D + lane] + aggSB[(size_t)sns * D + lane];
      float spi = 0.25f * wave_sum(oui * opi);
      float sni = 0.25f * wave_sum(oui * oni);
      float spp = 0.25f * wave_sum(oup * opp);
      float snp = 0.25f * wave_sum(oup * onp);
      // target graph
      float tui = tu_i[(size_t)u * D + lane] + aggTA[(size_t)sut * D + lane];
      float tup = tu_p[(size_t)u * D + lane] + aggTB[(size_t)sut * D + lane];
      float tpi_ = ti_i[(size_t)pt * D + lane] + aggTA[(size_t)spt * D + lane];
      float tpp_ = ti_p[(size_t)pt * D + lane] + aggTB[(size_t)spt * D + lane];
      float tni_ = ti_i[(size_t)nt * D + lane] + aggTA[(size_t)snt * D + lane];
      float tnp_ = ti_p[(size_t)nt * D + lane] + aggTB[(size_t)snt * D + lane];
      float tpi = 0.25f * wave_sum(tui * tpi_);
      float tni = 0.25f * wave_sum(tui * tni_);
      float tpp = 0.25f * wave_sum(tup * tpp_);
      float tnp = 0.25f * wave_sum(tup * tnp_);
      // masks
      int db = det[0], dc = det[1];
      float ms, mt;
      if (dc > 100) {
        ms = (((const float*)ms8)[b] != 0.f) ? 1.f : 0.f;
        mt = (((const float*)mt8)[b] != 0.f) ? 1.f : 0.f;
      } else if (db > 100) {
        ms = ms8[b] ? 1.f : 0.f;
        mt = mt8[b] ? 1.f : 0.f;
      } else {
        ms = ((const int*)ms8)[b] ? 1.f : 0.f;
        mt = ((const int*)mt8)[b] ? 1.f : 0.f;
      }
      float l_int_s = ms * softplus_f(sni - spi);
      float l_pop_s = ms * softplus_f(spp - snp) + (1.f - ms) * softplus_f(snp - spp);
      float l_tot_s = softplus_f((sni + snp) - (spi + spp));
      float l_int_t = mt * softplus_f(tni - tpi);
      float l_pop_t = mt * softplus_f(tpp - tnp) + (1.f - mt) * softplus_f(tnp - tpp);
      float l_tot_t = softplus_f((tni + tnp) - (tpi + tpp));
      contrib = (l_tot_s + l_tot_t + 0.1f * (l_int_s + l_int_t) +
                 0.1f * (l_pop_s + l_pop_t)) * (1.f / (float)B);
    }
    __shared__ float wsum_[4];
    if (lane == 0) wsum_[threadIdx.x >> 6] = contrib;  // contrib is wave-uniform
    __syncthreads();
    if (threadIdx.x == 0) {
      dots_part[blockIdx.x] = wsum_[0] + wsum_[1] + wsum_[2] + wsum_[3];
    }
    return;
  }
  // ---- masked-L1 chunk scan ----
  int blk = blockIdx.x - DOTS_BLOCKS;
  int wave = (blk * blockDim.x + threadIdx.x) >> 6;
  int nwaves = (L1_BLOCKS * 256) >> 6;
  float a1 = 0.f, a2 = 0.f, a3 = 0.f, a4 = 0.f;
  float c5 = 0.f, c6 = 0.f, c7 = 0.f;
  for (int ch = wave; ch < NCHUNK; ch += nwaves) {
    int r0 = ch * 64;
    int r = r0 + lane;
    int flag = -1;
    if (r < NROWS_ALL) flag = (r < NS) ? map_s[r] : map_t[r - SI_N];
    bool valid = flag >= 0;
    unsigned long long m0 = __ballot(valid && r < U_N);
    unsigned long long m1 = __ballot(valid && r >= U_N && r < NS);
    unsigned long long m2 = __ballot(valid && r >= NS);
    if (lane == 0) {
      c5 += (float)__popcll(m0);
      c6 += (float)__popcll(m1);
      c7 += (float)__popcll(m2);
    }
    unsigned long long mm = m0 | m1 | m2;
    while (mm) {
      int bit = __ffsll((unsigned long long)mm) - 1;
      mm &= mm - 1;
      int rr = r0 + bit;
      if (rr < U_N) {
        size_t o = (size_t)rr * D + lane;
        a1 += fabsf(su_i[o] - su_p[o]);
        a3 += fabsf(tu_i[o] - tu_p[o]);
      } else if (rr < NS) {
        size_t o = (size_t)(rr - U_N) * D + lane;
        a2 += fabsf(si_i[o] - si_p[o]);
      } else {
        size_t o = (size_t)(rr - NS) * D + lane;
        a4 += fabsf(ti_i[o] - ti_p[o]);
      }
    }
  }
  a1 = wave_sum(a1);
  a2 = wave_sum(a2);
  a3 = wave_sum(a3);
  a4 = wave_sum(a4);
  __shared__ float sb[4][8];
  if (lane == 0) {
    int w = threadIdx.x >> 6;
    sb[w][0] = a1; sb[w][1] = a2; sb[w][2] = a3; sb[w][3] = a4;
    sb[w][4] = c5; sb[w][5] = c6; sb[w][6] = c7;
  }
  __syncthreads();
  int t = threadIdx.x;
  if (t < 7) {
    // each quantity q lives in its own contiguous array of L1_BLOCKS floats
    l1_part[t * L1_BLOCKS + blk] = sb[0][t] + sb[1][t] + sb[2][t] + sb[3][t];
  }
}

// ---------------------------------------------------------------------------
// Final reduce: one block sums the per-block partials (visible via stream
// ordering) and writes the scalar output. ~7.4K coalesced floats.
__global__ __launch_bounds__(256) void k_finish(
    const float* __restrict__ dots_part, const float* __restrict__ l1_part,
    float* __restrict__ out) {
  int t = threadIdx.x, lane = t & 63, w = t >> 6;
  float a0 = 0.f;
  for (int i = t; i < DOTS_BLOCKS; i += 256) a0 += dots_part[i];
  float q[7];
#pragma unroll
  for (int j = 0; j < 7; ++j) {
    float s = 0.f;
    for (int i = t; i < L1_BLOCKS; i += 256) s += l1_part[j * L1_BLOCKS + i];
    q[j] = s;
  }
  a0 = wave_sum(a0);
#pragma unroll
  for (int j = 0; j < 7; ++j) q[j] = wave_sum(q[j]);
  __shared__ float red[4][8];
  if (lane == 0) {
    red[w][0] = a0;
#pragma unroll
    for (int j = 0; j < 7; ++j) red[w][1 + j] = q[j];
  }
  __syncthreads();
  if (t == 0) {
    float v[8];
#pragma unroll
    for (int j = 0; j < 8; ++j)
      v[j] = red[0][j] + red[1][j] + red[2][j] + red[3][j];
    float n1 = v[1], n2 = v[2], n3 = v[3], n4 = v[4];
    float cu = fmaxf(v[5], 1.f);
    float cs = fmaxf(v[6], 1.f);
    float ct = fmaxf(v[7], 1.f);
    float dis = (n1 + n3) / (cu * (float)D) + n2 / (cs * (float)D) +
                n4 / (ct * (float)D);
    out[0] = v[0] - 0.01f * dis;
  }
}

// ---------------------------------------------------------------------------
extern "C" void kernel_launch(void* const* d_in, const int* in_sizes, int n_in,
                              void* d_out, int out_size, void* d_ws, size_t ws_size,
                              hipStream_t stream) {
  const int* user = (const int*)d_in[0];
  const int* spos = (const int*)d_in[1];
  const int* sneg = (const int*)d_in[2];
  const int* tpos = (const int*)d_in[3];
  const int* tneg = (const int*)d_in[4];
  const unsigned char* mask_s = (const unsigned char*)d_in[5];
  const unsigned char* mask_t = (const unsigned char*)d_in[6];
  const float* su_int = (const float*)d_in[7];
  const float* si_int = (const float*)d_in[8];
  const float* tu_int = (const float*)d_in[9];
  const float* ti_int = (const float*)d_in[10];
  const float* su_pop = (const float*)d_in[11];
  const float* si_pop = (const float*)d_in[12];
  const float* tu_pop = (const float*)d_in[13];
  const float* ti_pop = (const float*)d_in[14];
  const int* s_rows = (const int*)d_in[15];
  const int* s_cols = (const int*)d_in[16];
  const float* s_vals = (const float*)d_in[17];
  const int* t_rows = (const int*)d_in[18];
  const int* t_cols = (const int*)d_in[19];
  const float* t_vals = (const float*)d_in[20];
  const float* drop_s_int = (const float*)d_in[21];
  const float* drop_t_int = (const float*)d_in[22];
  const float* drop_s_pop = (const float*)d_in[23];
  const float* drop_t_pop = (const float*)d_in[24];
  const int nnz_s = in_sizes[15];
  const int nnz_t = in_sizes[18];

  // Workspace layout (~64 MB). int4 arrays first for 16B alignment.
  int4* bucket_s = (int4*)d_ws;                         // SLOTS*CAP
  int4* bucket_t = bucket_s + (size_t)SLOTS * CAP;      // SLOTS*CAP
  int4* ov_s = bucket_t + (size_t)SLOTS * CAP;          // OVCAP
  int4* ov_t = ov_s + OVCAP;                            // OVCAP
  float* aggSA = (float*)(ov_t + OVCAP);                // SLOTS*D
  float* aggSB = aggSA + (size_t)SLOTS * D;             // SLOTS*D
  float* aggTA = aggSB + (size_t)SLOTS * D;             // SLOTS*D
  float* aggTB = aggTA + (size_t)SLOTS * D;             // SLOTS*D
  float* dots_part = aggTB + (size_t)SLOTS * D;         // DOTS_BLOCKS
  float* l1_part = dots_part + DOTS_BLOCKS;             // 7*L1_BLOCKS
  int* det = (int*)(l1_part + 7 * L1_BLOCKS);           // 2
  int* ovcnt_s = det + 2;                               // 1
  int* ovcnt_t = ovcnt_s + 1;                           // 1
  int* cnt_s = ovcnt_t + 1;                             // SLOTS
  int* cnt_t = cnt_s + SLOTS;                           // SLOTS
  int* map_s = cnt_t + SLOTS;                           // NS
  int* map_t = map_s + NS;                              // NT

  // zero det..cnt_t (contiguous); maps to -1. Partials need no init (every
  // slot is written unconditionally by its owning block).
  hipMemsetAsync(det, 0, (size_t)(2 + 2 + 2 * SLOTS) * sizeof(int), stream);
  hipMemsetAsync(map_s, 0xFF, (size_t)(NS + NT) * sizeof(int), stream);

  k_init<<<97, 256, 0, stream>>>(user, spos, sneg, tpos, tneg, map_s, map_t, mask_s, det);

  int sblocks = (nnz_s + 1023) / 1024;
  int tblocks = (nnz_t + 1023) / 1024;
  k_compact4<<<sblocks + tblocks, 256, 0, stream>>>(
      s_rows, s_cols, s_vals, drop_s_int, drop_s_pop,
      t_rows, t_cols, t_vals, drop_t_int, drop_t_pop,
      map_s, map_t, cnt_s, cnt_t, bucket_s, bucket_t,
      ovcnt_s, ovcnt_t, ov_s, ov_t, nnz_s, nnz_t, sblocks);

  k_accum_pair<<<2 * SLOTS / 4, 256, 0, stream>>>(
      cnt_s, bucket_s, ovcnt_s, ov_s, cnt_t, bucket_t, ovcnt_t, ov_t,
      su_int, si_int, su_pop, si_pop, tu_int, ti_int, tu_pop, ti_pop,
      aggSA, aggSB, aggTA, aggTB);

  k_tail<<<DOTS_BLOCKS + L1_BLOCKS, 256, 0, stream>>>(
      user, spos, sneg, tpos, tneg, mask_s, mask_t, det,
      su_int, si_int, su_pop, si_pop, tu_int, ti_int, tu_pop, ti_pop,
      map_s, map_t, aggSA, aggSB, aggTA, aggTB,
      dots_part, l1_part);

  k_finish<<<1, 256, 0, stream>>>(dots_part, l1_part, (float*)d_out);
}

// Round 6
// 398.423 us; speedup vs baseline: 1.2144x; 1.0157x over previous
//
#include <hip/hip_runtime.h>
#include <math.h>

// Problem constants (match reference file)
constexpr int U_N = 100000;
constexpr int SI_N = 50000;
constexpr int TI_N = 40000;
constexpr int D = 64;
constexpr int B = 8192;
constexpr int NS = U_N + SI_N;   // 150000 rows in source graph
constexpr int NT = U_N + TI_N;   // 140000 rows in target graph
constexpr int SLOTS = 3 * B;     // compact agg slots: users | pos items | neg items
constexpr int CAP = 48;          // bucket capacity per slot (Poisson lambda ~20; tail -> overflow list)
constexpr int OVCAP = 4096;      // overflow list capacity (statistically never used)
constexpr int NROWS_ALL = U_N + SI_N + TI_N;  // fused dis-loss row space
constexpr int NCHUNK = (NROWS_ALL + 63) / 64; // 64-row chunks for L1 scan
constexpr int DOTS_BLOCKS = B / 4;            // 2048 blocks, 4 waves each -> one wave/sample
constexpr int L1_BLOCKS = 768;

__device__ __forceinline__ float wave_sum(float x) {
#pragma unroll
  for (int m = 32; m; m >>= 1) x += __shfl_xor(x, m, 64);
  return x;
}

__device__ __forceinline__ float softplus_f(float z) {
  return fmaxf(z, 0.f) + log1pf(expf(-fabsf(z)));
}

// ---------------------------------------------------------------------------
// Fused: blocks 0..95 build row->slot maps; block 96 classifies mask layout.
__global__ __launch_bounds__(256) void k_init(
    const int* __restrict__ user, const int* __restrict__ spos, const int* __restrict__ sneg,
    const int* __restrict__ tpos, const int* __restrict__ tneg,
    int* __restrict__ map_s, int* __restrict__ map_t,
    const unsigned char* __restrict__ m, int* __restrict__ det) {
  if (blockIdx.x < 96) {
    int t = blockIdx.x * blockDim.x + threadIdx.x;  // < 3*B exactly
    if (t < B) {
      int u = user[t];
      map_s[u] = t;
      map_t[u] = t;
    } else if (t < 2 * B) {
      int b = t - B;
      map_s[U_N + spos[b]] = t;
      map_t[U_N + tpos[b]] = t;
    } else {
      int b = t - 2 * B;
      map_s[U_N + sneg[b]] = t;
      map_t[U_N + tneg[b]] = t;
    }
    return;
  }
  int t = threadIdx.x;
  int cb = 0, cc = 0;
  for (int i = t; i < B; i += 256) {
    unsigned char v = m[i];
    if ((i & 3) && v) cb++;
    if (v > 1) cc++;
  }
#pragma unroll
  for (int off = 32; off; off >>= 1) {
    cb += __shfl_xor(cb, off, 64);
    cc += __shfl_xor(cc, off, 64);
  }
  __shared__ int sb[4], sc[4];
  if ((t & 63) == 0) { sb[t >> 6] = cb; sc[t >> 6] = cc; }
  __syncthreads();
  if (t == 0) {
    det[0] = sb[0] + sb[1] + sb[2] + sb[3];
    det[1] = sc[0] + sc[1] + sc[2] + sc[3];
  }
}

// ---------------------------------------------------------------------------
// Phase A (both graphs): FOUR edges per thread, 16B streaming loads of all
// edge arrays. Bucket entries are 8 BYTES, lossless: drop values are exactly
// {0, 1.25} (bernoulli/0.8), so {v*di, v*dp} collapse to one float
// v' = v*max(di,dp) (bit-exact product) + two flag bits packed into the col
// word (col < 2^18; bits 30,31 free). Edges with both drops zero are skipped.
// This halves the scattered HBM write-RMW traffic vs 16B entries.
__device__ __forceinline__ void emit_edge(
    int slot, unsigned packed, float vp,
    int* __restrict__ cnt, int2* __restrict__ bucket,
    int* __restrict__ ovcnt, int4* __restrict__ ov) {
  int pos = atomicAdd(&cnt[slot], 1);
  if (pos < CAP) {
    bucket[(size_t)slot * CAP + pos] = make_int2((int)packed, __float_as_int(vp));
  } else {
    int o = atomicAdd(ovcnt, 1);
    if (o < OVCAP) {
      ov[o] = make_int4(slot, (int)packed, __float_as_int(vp), 0);
    }
  }
}

__global__ __launch_bounds__(256) void k_compact4(
    const int* __restrict__ s_rows, const int* __restrict__ s_cols,
    const float* __restrict__ s_vals,
    const float* __restrict__ dsi, const float* __restrict__ dsp,
    const int* __restrict__ t_rows, const int* __restrict__ t_cols,
    const float* __restrict__ t_vals,
    const float* __restrict__ dti, const float* __restrict__ dtp,
    const int* __restrict__ map_s, const int* __restrict__ map_t,
    int* __restrict__ cnt_s, int* __restrict__ cnt_t,
    int2* __restrict__ bucket_s, int2* __restrict__ bucket_t,
    int* __restrict__ ovcnt_s, int* __restrict__ ovcnt_t,
    int4* __restrict__ ov_s, int4* __restrict__ ov_t,
    int nnz_s, int nnz_t, int sblocks) {
  const int* rows;
  const int* cols;
  const float* vals;
  const float* di;
  const float* dp;
  const int* map;
  int* cnt;
  int2* bucket;
  int* ovcnt;
  int4* ov;
  int nnz;
  int blk = blockIdx.x;
  if (blk < sblocks) {
    rows = s_rows; cols = s_cols; vals = s_vals; di = dsi; dp = dsp;
    map = map_s; cnt = cnt_s; bucket = bucket_s; ovcnt = ovcnt_s; ov = ov_s;
    nnz = nnz_s;
  } else {
    blk -= sblocks;
    rows = t_rows; cols = t_cols; vals = t_vals; di = dti; dp = dtp;
    map = map_t; cnt = cnt_t; bucket = bucket_t; ovcnt = ovcnt_t; ov = ov_t;
    nnz = nnz_t;
  }
  int base = (blk * 256 + (int)threadIdx.x) * 4;
  if (base + 4 <= nnz) {
    // independent streaming loads (no dependence on map)
    int4 r4 = *(const int4*)(rows + base);
    int4 c4 = *(const int4*)(cols + base);
    float4 v4 = *(const float4*)(vals + base);
    float4 di4 = *(const float4*)(di + base);
    float4 dp4 = *(const float4*)(dp + base);
    // 4 independent map gathers
    int s0 = map[r4.x];
    int s1 = map[r4.y];
    int s2 = map[r4.z];
    int s3 = map[r4.w];
    unsigned b0 = (di4.x != 0.f ? 0x40000000u : 0u) | (dp4.x != 0.f ? 0x80000000u : 0u);
    unsigned b1 = (di4.y != 0.f ? 0x40000000u : 0u) | (dp4.y != 0.f ? 0x80000000u : 0u);
    unsigned b2 = (di4.z != 0.f ? 0x40000000u : 0u) | (dp4.z != 0.f ? 0x80000000u : 0u);
    unsigned b3 = (di4.w != 0.f ? 0x40000000u : 0u) | (dp4.w != 0.f ? 0x80000000u : 0u);
    if (s0 >= 0 && b0) emit_edge(s0, (unsigned)c4.x | b0, v4.x * fmaxf(di4.x, dp4.x), cnt, bucket, ovcnt, ov);
    if (s1 >= 0 && b1) emit_edge(s1, (unsigned)c4.y | b1, v4.y * fmaxf(di4.y, dp4.y), cnt, bucket, ovcnt, ov);
    if (s2 >= 0 && b2) emit_edge(s2, (unsigned)c4.z | b2, v4.z * fmaxf(di4.z, dp4.z), cnt, bucket, ovcnt, ov);
    if (s3 >= 0 && b3) emit_edge(s3, (unsigned)c4.w | b3, v4.w * fmaxf(di4.w, dp4.w), cnt, bucket, ovcnt, ov);
  } else {
    for (int e = base; e < nnz; ++e) {
      int slot = map[rows[e]];
      if (slot < 0) continue;
      unsigned bb = (di[e] != 0.f ? 0x40000000u : 0u) | (dp[e] != 0.f ? 0x80000000u : 0u);
      if (!bb) continue;
      emit_edge(slot, (unsigned)cols[e] | bb, vals[e] * fmaxf(di[e], dp[e]), cnt, bucket, ovcnt, ov);
    }
  }
}

// ---------------------------------------------------------------------------
// Phase B helper: group g=lane>>4 handles edges k+g..k+12+g; sub=lane&15
// handles dims [4sub,4sub+4). 8 independent float4 loads in flight per iter.
// Dependent-load chain: {cnt, payload} in parallel -> shfl -> embedding gathers.
__device__ __forceinline__ void accum_slot(
    int s, int lane,
    const int* __restrict__ cnt, const int2* __restrict__ bucket,
    const int* __restrict__ ovcnt, const int4* __restrict__ ov,
    const float* __restrict__ eu_i, const float* __restrict__ ei_i,
    const float* __restrict__ eu_p, const float* __restrict__ ei_p,
    float* __restrict__ aggA, float* __restrict__ aggB) {
  // issue both loads unconditionally so they overlap (payload of lanes >= m is
  // masked below; reading allocated-but-unused bucket memory is harmless)
  int li = min(lane, CAP - 1);
  int2 pl = bucket[(size_t)s * CAP + li];
  int m = min(cnt[s], CAP);
  int g = lane >> 4, sub = lane & 15;
  int c = 0;
  float wi = 0.f, wp = 0.f;
  if (lane < m) {
    unsigned packed = (unsigned)pl.x;
    float vp = __int_as_float(pl.y);
    c = (int)(packed & 0x3FFFFFFFu);
    wi = (packed & 0x40000000u) ? vp : 0.f;
    wp = (packed & 0x80000000u) ? vp : 0.f;
  }
  float aIx = 0, aIy = 0, aIz = 0, aIw = 0;
  float aPx = 0, aPy = 0, aPz = 0, aPw = 0;
  for (int k = 0; k < m; k += 16) {
    int i0 = k + g, i1 = k + 4 + g, i2 = k + 8 + g, i3 = k + 12 + g;  // <= 47
    int c0 = __shfl(c, i0, 64), c1 = __shfl(c, i1, 64);
    int c2 = __shfl(c, i2, 64), c3 = __shfl(c, i3, 64);
    float wi0 = __shfl(wi, i0, 64), wi1 = __shfl(wi, i1, 64);
    float wi2 = __shfl(wi, i2, 64), wi3 = __shfl(wi, i3, 64);
    float wp0 = __shfl(wp, i0, 64), wp1 = __shfl(wp, i1, 64);
    float wp2 = __shfl(wp, i2, 64), wp3 = __shfl(wp, i3, 64);
    const float* bi0 = (c0 < U_N) ? (eu_i + (size_t)c0 * D) : (ei_i + (size_t)(c0 - U_N) * D);
    const float* bi1 = (c1 < U_N) ? (eu_i + (size_t)c1 * D) : (ei_i + (size_t)(c1 - U_N) * D);
    const float* bi2 = (c2 < U_N) ? (eu_i + (size_t)c2 * D) : (ei_i + (size_t)(c2 - U_N) * D);
    const float* bi3 = (c3 < U_N) ? (eu_i + (size_t)c3 * D) : (ei_i + (size_t)(c3 - U_N) * D);
    const float* bp0 = (c0 < U_N) ? (eu_p + (size_t)c0 * D) : (ei_p + (size_t)(c0 - U_N) * D);
    const float* bp1 = (c1 < U_N) ? (eu_p + (size_t)c1 * D) : (ei_p + (size_t)(c1 - U_N) * D);
    const float* bp2 = (c2 < U_N) ? (eu_p + (size_t)c2 * D) : (ei_p + (size_t)(c2 - U_N) * D);
    const float* bp3 = (c3 < U_N) ? (eu_p + (size_t)c3 * D) : (ei_p + (size_t)(c3 - U_N) * D);
    float4 vI0 = *(const float4*)(bi0 + 4 * sub);
    float4 vI1 = *(const float4*)(bi1 + 4 * sub);
    float4 vI2 = *(const float4*)(bi2 + 4 * sub);
    float4 vI3 = *(const float4*)(bi3 + 4 * sub);
    float4 vP0 = *(const float4*)(bp0 + 4 * sub);
    float4 vP1 = *(const float4*)(bp1 + 4 * sub);
    float4 vP2 = *(const float4*)(bp2 + 4 * sub);
    float4 vP3 = *(const float4*)(bp3 + 4 * sub);
    aIx = fmaf(wi0, vI0.x, aIx); aIy = fmaf(wi0, vI0.y, aIy);
    aIz = fmaf(wi0, vI0.z, aIz); aIw = fmaf(wi0, vI0.w, aIw);
    aIx = fmaf(wi1, vI1.x, aIx); aIy = fmaf(wi1, vI1.y, aIy);
    aIz = fmaf(wi1, vI1.z, aIz); aIw = fmaf(wi1, vI1.w, aIw);
    aIx = fmaf(wi2, vI2.x, aIx); aIy = fmaf(wi2, vI2.y, aIy);
    aIz = fmaf(wi2, vI2.z, aIz); aIw = fmaf(wi2, vI2.w, aIw);
    aIx = fmaf(wi3, vI3.x, aIx); aIy = fmaf(wi3, vI3.y, aIy);
    aIz = fmaf(wi3, vI3.z, aIz); aIw = fmaf(wi3, vI3.w, aIw);
    aPx = fmaf(wp0, vP0.x, aPx); aPy = fmaf(wp0, vP0.y, aPy);
    aPz = fmaf(wp0, vP0.z, aPz); aPw = fmaf(wp0, vP0.w, aPw);
    aPx = fmaf(wp1, vP1.x, aPx); aPy = fmaf(wp1, vP1.y, aPy);
    aPz = fmaf(wp1, vP1.z, aPz); aPw = fmaf(wp1, vP1.w, aPw);
    aPx = fmaf(wp2, vP2.x, aPx); aPy = fmaf(wp2, vP2.y, aPy);
    aPz = fmaf(wp2, vP2.z, aPz); aPw = fmaf(wp2, vP2.w, aPw);
    aPx = fmaf(wp3, vP3.x, aPx); aPy = fmaf(wp3, vP3.y, aPy);
    aPz = fmaf(wp3, vP3.z, aPz); aPw = fmaf(wp3, vP3.w, aPw);
  }
#define XRED(x) x += __shfl_xor(x, 16, 64); x += __shfl_xor(x, 32, 64);
  XRED(aIx) XRED(aIy) XRED(aIz) XRED(aIw)
  XRED(aPx) XRED(aPy) XRED(aPz) XRED(aPw)
#undef XRED
  // overflow fixup by owner wave (normally nov==0); ov entries carry payload
  int nov = min(*ovcnt, OVCAP);
  for (int i = 0; i < nov; ++i) {
    int4 q = ov[i];
    if (q.x == s) {
      unsigned packed = (unsigned)q.y;
      float vp = __int_as_float(q.z);
      int cc = (int)(packed & 0x3FFFFFFFu);
      float wwi = (packed & 0x40000000u) ? vp : 0.f;
      float wwp = (packed & 0x80000000u) ? vp : 0.f;
      const float* bi = (cc < U_N) ? (eu_i + (size_t)cc * D) : (ei_i + (size_t)(cc - U_N) * D);
      const float* bp = (cc < U_N) ? (eu_p + (size_t)cc * D) : (ei_p + (size_t)(cc - U_N) * D);
      if (lane < 16) {
        float4 vI = *(const float4*)(bi + 4 * sub);
        float4 vP = *(const float4*)(bp + 4 * sub);
        aIx = fmaf(wwi, vI.x, aIx); aIy = fmaf(wwi, vI.y, aIy);
        aIz = fmaf(wwi, vI.z, aIz); aIw = fmaf(wwi, vI.w, aIw);
        aPx = fmaf(wwp, vP.x, aPx); aPy = fmaf(wwp, vP.y, aPy);
        aPz = fmaf(wwp, vP.z, aPz); aPw = fmaf(wwp, vP.w, aPw);
      }
    }
  }
  if (lane < 16) {
    *(float4*)(aggA + (size_t)s * D + 4 * sub) = make_float4(aIx, aIy, aIz, aIw);
    *(float4*)(aggB + (size_t)s * D + 4 * sub) = make_float4(aPx, aPy, aPz, aPw);
  }
}

// Both graphs in one dispatch: sg<SLOTS source, else target.
__global__ __launch_bounds__(256) void k_accum_pair(
    const int* __restrict__ cnt_s, const int2* __restrict__ bucket_s,
    const int* __restrict__ ovcnt_s, const int4* __restrict__ ov_s,
    const int* __restrict__ cnt_t, const int2* __restrict__ bucket_t,
    const int* __restrict__ ovcnt_t, const int4* __restrict__ ov_t,
    const float* __restrict__ su_i, const float* __restrict__ si_i,
    const float* __restrict__ su_p, const float* __restrict__ si_p,
    const float* __restrict__ tu_i, const float* __restrict__ ti_i,
    const float* __restrict__ tu_p, const float* __restrict__ ti_p,
    float* __restrict__ aggSA, float* __restrict__ aggSB,
    float* __restrict__ aggTA, float* __restrict__ aggTB) {
  int lane = threadIdx.x & 63;
  int sg = (blockIdx.x * 256 + threadIdx.x) >> 6;
  if (sg >= 2 * SLOTS) return;
  if (sg < SLOTS) {
    accum_slot(sg, lane, cnt_s, bucket_s, ovcnt_s, ov_s,
               su_i, si_i, su_p, si_p, aggSA, aggSB);
  } else {
    accum_slot(sg - SLOTS, lane, cnt_t, bucket_t, ovcnt_t, ov_t,
               tu_i, ti_i, tu_p, ti_p, aggTA, aggTB);
  }
}

// ---------------------------------------------------------------------------
// Fused tail: blocks [0, DOTS_BLOCKS) = one wave per sample, all 8 dots + BPR
// losses; blocks [DOTS_BLOCKS, DOTS_BLOCKS+L1_BLOCKS) = masked-L1 chunk scan.
// NO contended atomics: every block writes plain stores to its OWN partial
// slots; a separate 1-block k_finish kernel (stream-ordered) reduces them.
__global__ __launch_bounds__(256) void k_tail(
    const int* __restrict__ user,
    const int* __restrict__ spos, const int* __restrict__ sneg,
    const int* __restrict__ tpos, const int* __restrict__ tneg,
    const unsigned char* __restrict__ ms8, const unsigned char* __restrict__ mt8,
    const int* __restrict__ det,
    const float* __restrict__ su_i, const float* __restrict__ si_i,
    const float* __restrict__ su_p, const float* __restrict__ si_p,
    const float* __restrict__ tu_i, const float* __restrict__ ti_i,
    const float* __restrict__ tu_p, const float* __restrict__ ti_p,
    const int* __restrict__ map_s, const int* __restrict__ map_t,
    const float* __restrict__ aggSA, const float* __restrict__ aggSB,
    const float* __restrict__ aggTA, const float* __restrict__ aggTB,
    float* __restrict__ dots_part, float* __restrict__ l1_part) {
  int lane = threadIdx.x & 63;
  if (blockIdx.x < DOTS_BLOCKS) {
    // ---- dots + BPR losses ----
    int b = (blockIdx.x * blockDim.x + threadIdx.x) >> 6;
    float contrib = 0.f;
    {
      int u = user[b];
      int ps = spos[b], ns = sneg[b], pt = tpos[b], nt = tneg[b];
      int sus = map_s[u], sps = map_s[U_N + ps], sns = map_s[U_N + ns];
      int sut = map_t[u], spt = map_t[U_N + pt], snt = map_t[U_N + nt];
      // source graph
      float oui = su_i[(size_t)u * D + lane] + aggSA[(size_t)sus * D + lane];
      float oup = su_p[(size_t)u * D + lane] + aggSB[(size_t)sus * D + lane];
      float opi = si_i[(size_t)ps * D + lane] + aggSA[(size_t)sps * D + lane];
      float opp = si_p[(size_t)ps * D + lane] + aggSB[(size_t)sps * D + lane];
      float oni = si_i[(size_t)ns * D + lane] + aggSA[(size_t)sns * D + lane];
      float onp = si_p[(size_t)ns * D + lane] + aggSB[(size_t)sns * D + lane];
      float spi = 0.25f * wave_sum(oui * opi);
      float sni = 0.25f * wave_sum(oui * oni);
      float spp = 0.25f * wave_sum(oup * opp);
      float snp = 0.25f * wave_sum(oup * onp);
      // target graph
      float tui = tu_i[(size_t)u * D + lane] + aggTA[(size_t)sut * D + lane];
      float tup = tu_p[(size_t)u * D + lane] + aggTB[(size_t)sut * D + lane];
      float tpi_ = ti_i[(size_t)pt * D + lane] + aggTA[(size_t)spt * D + lane];
      float tpp_ = ti_p[(size_t)pt * D + lane] + aggTB[(size_t)spt * D + lane];
      float tni_ = ti_i[(size_t)nt * D + lane] + aggTA[(size_t)snt * D + lane];
      float tnp_ = ti_p[(size_t)nt * D + lane] + aggTB[(size_t)snt * D + lane];
      float tpi = 0.25f * wave_sum(tui * tpi_);
      float tni = 0.25f * wave_sum(tui * tni_);
      float tpp = 0.25f * wave_sum(tup * tpp_);
      float tnp = 0.25f * wave_sum(tup * tnp_);
      // masks
      int db = det[0], dc = det[1];
      float ms, mt;
      if (dc > 100) {
        ms = (((const float*)ms8)[b] != 0.f) ? 1.f : 0.f;
        mt = (((const float*)mt8)[b] != 0.f) ? 1.f : 0.f;
      } else if (db > 100) {
        ms = ms8[b] ? 1.f : 0.f;
        mt = mt8[b] ? 1.f : 0.f;
      } else {
        ms = ((const int*)ms8)[b] ? 1.f : 0.f;
        mt = ((const int*)mt8)[b] ? 1.f : 0.f;
      }
      float l_int_s = ms * softplus_f(sni - spi);
      float l_pop_s = ms * softplus_f(spp - snp) + (1.f - ms) * softplus_f(snp - spp);
      float l_tot_s = softplus_f((sni + snp) - (spi + spp));
      float l_int_t = mt * softplus_f(tni - tpi);
      float l_pop_t = mt * softplus_f(tpp - tnp) + (1.f - mt) * softplus_f(tnp - tpp);
      float l_tot_t = softplus_f((tni + tnp) - (tpi + tpp));
      contrib = (l_tot_s + l_tot_t + 0.1f * (l_int_s + l_int_t) +
                 0.1f * (l_pop_s + l_pop_t)) * (1.f / (float)B);
    }
    __shared__ float wsum_[4];
    if (lane == 0) wsum_[threadIdx.x >> 6] = contrib;  // contrib is wave-uniform
    __syncthreads();
    if (threadIdx.x == 0) {
      dots_part[blockIdx.x] = wsum_[0] + wsum_[1] + wsum_[2] + wsum_[3];
    }
    return;
  }
  // ---- masked-L1 chunk scan ----
  int blk = blockIdx.x - DOTS_BLOCKS;
  int wave = (blk * blockDim.x + threadIdx.x) >> 6;
  int nwaves = (L1_BLOCKS * 256) >> 6;
  float a1 = 0.f, a2 = 0.f, a3 = 0.f, a4 = 0.f;
  float c5 = 0.f, c6 = 0.f, c7 = 0.f;
  for (int ch = wave; ch < NCHUNK; ch += nwaves) {
    int r0 = ch * 64;
    int r = r0 + lane;
    int flag = -1;
    if (r < NROWS_ALL) flag = (r < NS) ? map_s[r] : map_t[r - SI_N];
    bool valid = flag >= 0;
    unsigned long long m0 = __ballot(valid && r < U_N);
    unsigned long long m1 = __ballot(valid && r >= U_N && r < NS);
    unsigned long long m2 = __ballot(valid && r >= NS);
    if (lane == 0) {
      c5 += (float)__popcll(m0);
      c6 += (float)__popcll(m1);
      c7 += (float)__popcll(m2);
    }
    unsigned long long mm = m0 | m1 | m2;
    while (mm) {
      int bit = __ffsll((unsigned long long)mm) - 1;
      mm &= mm - 1;
      int rr = r0 + bit;
      if (rr < U_N) {
        size_t o = (size_t)rr * D + lane;
        a1 += fabsf(su_i[o] - su_p[o]);
        a3 += fabsf(tu_i[o] - tu_p[o]);
      } else if (rr < NS) {
        size_t o = (size_t)(rr - U_N) * D + lane;
        a2 += fabsf(si_i[o] - si_p[o]);
      } else {
        size_t o = (size_t)(rr - NS) * D + lane;
        a4 += fabsf(ti_i[o] - ti_p[o]);
      }
    }
  }
  a1 = wave_sum(a1);
  a2 = wave_sum(a2);
  a3 = wave_sum(a3);
  a4 = wave_sum(a4);
  __shared__ float sb[4][8];
  if (lane == 0) {
    int w = threadIdx.x >> 6;
    sb[w][0] = a1; sb[w][1] = a2; sb[w][2] = a3; sb[w][3] = a4;
    sb[w][4] = c5; sb[w][5] = c6; sb[w][6] = c7;
  }
  __syncthreads();
  int t = threadIdx.x;
  if (t < 7) {
    // each quantity q lives in its own contiguous array of L1_BLOCKS floats
    l1_part[t * L1_BLOCKS + blk] = sb[0][t] + sb[1][t] + sb[2][t] + sb[3][t];
  }
}

// ---------------------------------------------------------------------------
// Final reduce: one block sums the per-block partials (visible via stream
// ordering) and writes the scalar output. ~7.4K coalesced floats.
__global__ __launch_bounds__(256) void k_finish(
    const float* __restrict__ dots_part, const float* __restrict__ l1_part,
    float* __restrict__ out) {
  int t = threadIdx.x, lane = t & 63, w = t >> 6;
  float a0 = 0.f;
  for (int i = t; i < DOTS_BLOCKS; i += 256) a0 += dots_part[i];
  float q[7];
#pragma unroll
  for (int j = 0; j < 7; ++j) {
    float s = 0.f;
    for (int i = t; i < L1_BLOCKS; i += 256) s += l1_part[j * L1_BLOCKS + i];
    q[j] = s;
  }
  a0 = wave_sum(a0);
#pragma unroll
  for (int j = 0; j < 7; ++j) q[j] = wave_sum(q[j]);
  __shared__ float red[4][8];
  if (lane == 0) {
    red[w][0] = a0;
#pragma unroll
    for (int j = 0; j < 7; ++j) red[w][1 + j] = q[j];
  }
  __syncthreads();
  if (t == 0) {
    float v[8];
#pragma unroll
    for (int j = 0; j < 8; ++j)
      v[j] = red[0][j] + red[1][j] + red[2][j] + red[3][j];
    float n1 = v[1], n2 = v[2], n3 = v[3], n4 = v[4];
    float cu = fmaxf(v[5], 1.f);
    float cs = fmaxf(v[6], 1.f);
    float ct = fmaxf(v[7], 1.f);
    float dis = (n1 + n3) / (cu * (float)D) + n2 / (cs * (float)D) +
                n4 / (ct * (float)D);
    out[0] = v[0] - 0.01f * dis;
  }
}

// ---------------------------------------------------------------------------
extern "C" void kernel_launch(void* const* d_in, const int* in_sizes, int n_in,
                              void* d_out, int out_size, void* d_ws, size_t ws_size,
                              hipStream_t stream) {
  const int* user = (const int*)d_in[0];
  const int* spos = (const int*)d_in[1];
  const int* sneg = (const int*)d_in[2];
  const int* tpos = (const int*)d_in[3];
  const int* tneg = (const int*)d_in[4];
  const unsigned char* mask_s = (const unsigned char*)d_in[5];
  const unsigned char* mask_t = (const unsigned char*)d_in[6];
  const float* su_int = (const float*)d_in[7];
  const float* si_int = (const float*)d_in[8];
  const float* tu_int = (const float*)d_in[9];
  const float* ti_int = (const float*)d_in[10];
  const float* su_pop = (const float*)d_in[11];
  const float* si_pop = (const float*)d_in[12];
  const float* tu_pop = (const float*)d_in[13];
  const float* ti_pop = (const float*)d_in[14];
  const int* s_rows = (const int*)d_in[15];
  const int* s_cols = (const int*)d_in[16];
  const float* s_vals = (const float*)d_in[17];
  const int* t_rows = (const int*)d_in[18];
  const int* t_cols = (const int*)d_in[19];
  const float* t_vals = (const float*)d_in[20];
  const float* drop_s_int = (const float*)d_in[21];
  const float* drop_t_int = (const float*)d_in[22];
  const float* drop_s_pop = (const float*)d_in[23];
  const float* drop_t_pop = (const float*)d_in[24];
  const int nnz_s = in_sizes[15];
  const int nnz_t = in_sizes[18];

  // Workspace layout (~46 MB). Widest-aligned arrays first.
  int4* ov_s = (int4*)d_ws;                             // OVCAP
  int4* ov_t = ov_s + OVCAP;                            // OVCAP
  int2* bucket_s = (int2*)(ov_t + OVCAP);               // SLOTS*CAP (8B entries)
  int2* bucket_t = bucket_s + (size_t)SLOTS * CAP;      // SLOTS*CAP
  float* aggSA = (float*)(bucket_t + (size_t)SLOTS * CAP);  // SLOTS*D
  float* aggSB = aggSA + (size_t)SLOTS * D;             // SLOTS*D
  float* aggTA = aggSB + (size_t)SLOTS * D;             // SLOTS*D
  float* aggTB = aggTA + (size_t)SLOTS * D;             // SLOTS*D
  float* dots_part = aggTB + (size_t)SLOTS * D;         // DOTS_BLOCKS
  float* l1_part = dots_part + DOTS_BLOCKS;             // 7*L1_BLOCKS
  int* det = (int*)(l1_part + 7 * L1_BLOCKS);           // 2
  int* ovcnt_s = det + 2;                               // 1
  int* ovcnt_t = ovcnt_s + 1;                           // 1
  int* cnt_s = ovcnt_t + 1;                             // SLOTS
  int* cnt_t = cnt_s + SLOTS;                           // SLOTS
  int* map_s = cnt_t + SLOTS;                           // NS
  int* map_t = map_s + NS;                              // NT

  // zero det..cnt_t (contiguous); maps to -1. Partials need no init (every
  // slot is written unconditionally by its owning block).
  hipMemsetAsync(det, 0, (size_t)(2 + 2 + 2 * SLOTS) * sizeof(int), stream);
  hipMemsetAsync(map_s, 0xFF, (size_t)(NS + NT) * sizeof(int), stream);

  k_init<<<97, 256, 0, stream>>>(user, spos, sneg, tpos, tneg, map_s, map_t, mask_s, det);

  int sblocks = (nnz_s + 1023) / 1024;
  int tblocks = (nnz_t + 1023) / 1024;
  k_compact4<<<sblocks + tblocks, 256, 0, stream>>>(
      s_rows, s_cols, s_vals, drop_s_int, drop_s_pop,
      t_rows, t_cols, t_vals, drop_t_int, drop_t_pop,
      map_s, map_t, cnt_s, cnt_t, bucket_s, bucket_t,
      ovcnt_s, ovcnt_t, ov_s, ov_t, nnz_s, nnz_t, sblocks);

  k_accum_pair<<<2 * SLOTS / 4, 256, 0, stream>>>(
      cnt_s, bucket_s, ovcnt_s, ov_s, cnt_t, bucket_t, ovcnt_t, ov_t,
      su_int, si_int, su_pop, si_pop, tu_int, ti_int, tu_pop, ti_pop,
      aggSA, aggSB, aggTA, aggTB);

  k_tail<<<DOTS_BLOCKS + L1_BLOCKS, 256, 0, stream>>>(
      user, spos, sneg, tpos, tneg, mask_s, mask_t, det,
      su_int, si_int, su_pop, si_pop, tu_int, ti_int, tu_pop, ti_pop,
      map_s, map_t, aggSA, aggSB, aggTA, aggTB,
      dots_part, l1_part);

  k_finish<<<1, 256, 0, stream>>>(dots_part, l1_part, (float*)d_out);
}